// Round 11
// baseline (144.279 us; speedup 1.0000x reference)
//
#include <hip/hip_runtime.h>
#include <math.h>

#define N_NODES 50000
#define N_EDGES 800000
#define CAP 64     // max out-degree bucket capacity (realized max ~40, Poisson(16))
#define NBE 391    // encode blocks: ceil(50000/128)
#define NBS 3125   // scatter blocks: ceil(800000/256)

typedef __attribute__((ext_vector_type(8)))  short s16x8;   // 8 bf16 (4 VGPR)
typedef __attribute__((ext_vector_type(16))) float f32x16;  // MFMA acc
typedef unsigned int u32;
typedef unsigned short u16;

union U16B { uint4 u; s16x8 s; };

// f32 -> bf16 bits, round-to-nearest-even
__device__ __forceinline__ u32 bfr(float f) {
    u32 u = __float_as_uint(f);
    return (u + 0x7FFFu + ((u >> 16) & 1u)) >> 16;
}
__device__ __forceinline__ u32 pkbf(float a, float b) { return bfr(a) | (bfr(b) << 16); }
__device__ __forceinline__ float bf2f(u32 b) { return __uint_as_float(b << 16); }
// dot of a bf16x2 pair against another
__device__ __forceinline__ float dotpair(u32 a, u32 b) {
    return bf2f(a & 0xFFFFu) * bf2f(b & 0xFFFFu) + bf2f(a >> 16) * bf2f(b >> 16);
}

// Build an MFMA input frag (lane-dim = D-col, k = 8*(lane>>5)+e) from 8 f32
// D-regs of a 32x32x16 accumulator (rows (r&3)+8*(r>>2)+4*hh), via bf16 pack
// + half-wave exchange. d8 must be compile-time indexed by caller.
__device__ __forceinline__ uint4 buildfrag(const float* d8, int hh) {
    u32 P = pkbf(d8[0], d8[1]), Q = pkbf(d8[2], d8[3]);
    u32 R = pkbf(d8[4], d8[5]), S = pkbf(d8[6], d8[7]);
    u32 sP = (u32)__shfl_xor((int)P, 32);
    u32 sQ = (u32)__shfl_xor((int)Q, 32);
    u32 sR = (u32)__shfl_xor((int)R, 32);
    u32 sS = (u32)__shfl_xor((int)S, 32);
    uint4 f;
    f.x = hh ? sR : P;  f.y = hh ? sS : Q;
    f.z = hh ? R : sP;  f.w = hh ? S : sQ;
    return f;
}
#define BUILDF(OUT, ACC, Q, HH) do { \
    float _td[8]; \
    _Pragma("unroll") for (int _z = 0; _z < 8; ++_z) _td[_z] = (ACC)[(Q)*8 + _z]; \
    (OUT) = buildfrag(_td, HH); } while (0)
#define BUILDR(OUT, ACC, Q, HH) do { \
    float _td[8]; \
    _Pragma("unroll") for (int _z = 0; _z < 8; ++_z) _td[_z] = fmaxf((ACC)[(Q)*8 + _z], 0.f); \
    (OUT) = buildfrag(_td, HH); } while (0)

// ---------------------------------------------------------------------------
// prep: weights -> bf16, transposed [col][k] rows (256B), granule-XOR swizzled
// ---------------------------------------------------------------------------
__global__ __launch_bounds__(256) void k_prep(
    const float* __restrict__ enc_w, const float* __restrict__ msg_w,
    const float* __restrict__ sig_w, const float* __restrict__ agg_w,
    const float* __restrict__ dec_w,
    uint4* __restrict__ WtE, uint4* __restrict__ WtM, uint4* __restrict__ WtD,
    uint4* __restrict__ WtA0, uint4* __restrict__ WtA1, uint4* __restrict__ WtS)
{
    int gid = blockIdx.x * 256 + threadIdx.x;
    if (gid < 10240) {
        int m = gid >> 11, r = gid & 2047;
        int col = r >> 4, s = r & 15;
        const float* W; uint4* D; int kb = 0;
        if      (m == 0) { W = enc_w; D = WtE; }
        else if (m == 1) { W = msg_w; D = WtM; }
        else if (m == 2) { W = dec_w; D = WtD; }
        else if (m == 3) { W = agg_w; D = WtA0; }
        else             { W = agg_w; D = WtA1; kb = 128; }
        float v[8];
        #pragma unroll
        for (int j = 0; j < 8; ++j) v[j] = W[(size_t)(kb + s * 8 + j) * 128 + col];
        uint4 w;
        w.x = pkbf(v[0], v[1]); w.y = pkbf(v[2], v[3]);
        w.z = pkbf(v[4], v[5]); w.w = pkbf(v[6], v[7]);
        D[col * 16 + (s ^ (col & 7))] = w;
    } else if (gid < 10752) {
        int r = gid - 10240;
        int row = r >> 4, s = r & 15;
        float v[8];
        #pragma unroll
        for (int j = 0; j < 8; ++j)
            v[j] = (row < 16) ? sig_w[(size_t)(s * 8 + j) * 16 + row] : 0.0f;
        uint4 w;
        w.x = pkbf(v[0], v[1]); w.y = pkbf(v[2], v[3]);
        w.z = pkbf(v[4], v[5]); w.w = pkbf(v[6], v[7]);
        WtS[row * 16 + (s ^ (row & 7))] = w;
    }
}

// ---------------------------------------------------------------------------
// fused encode + scatter (grid-level task fusion; independent phases):
//   blockIdx <  NBE : MFMA encode (h, msg, sig)
//   blockIdx >= NBE : edge scatter — pos = atomicAdd(counts[src]), bucket = dst
// ---------------------------------------------------------------------------
__global__ __launch_bounds__(256) void k_enc_scat(
    const float* __restrict__ x,
    const uint4* __restrict__ WtE, const uint4* __restrict__ WtM,
    const uint4* __restrict__ WtS,
    const float* __restrict__ enc_b, const float* __restrict__ sig_b,
    const float* __restrict__ msg_b,
    uint4* __restrict__ h_g, u32* __restrict__ sig_bf, uint4* __restrict__ msg_g,
    const int* __restrict__ src, const int* __restrict__ dst,
    int* __restrict__ counts, u32* __restrict__ bucket)
{
    __shared__ uint4 LB[2048];   // x tile bf16 [128 nodes][16 granules]
    __shared__ uint4 LW[2048];   // weight tile [128 cols][16 granules]
    __shared__ float LS[2176];   // sigWt (8KB) then sig funnel (8.7KB)

    const int t = threadIdx.x;

    if (blockIdx.x >= NBE) {
        // ---------------- scatter path (no LDS use) ----------------
        int e = (blockIdx.x - NBE) * 256 + t;
        if (e < N_EDGES) {
            int s = src[e], d = dst[e];
            int pos = atomicAdd(&counts[s], 1);
            bucket[(size_t)s * CAP + pos] = (u32)d;
        }
        return;
    }

    // ---------------- encode path ----------------
    const int node0 = blockIdx.x * 128;
    int nrem = N_NODES - node0; if (nrem > 128) nrem = 128;
    const int lane = t & 63, wid = t >> 6;
    const int l31 = lane & 31, hh = lane >> 5;
    const int nloc = wid * 32 + l31;
    const int sw7 = l31 & 7;

    // stage x (f32->bf16, swizzled) + enc weights
    #pragma unroll
    for (int it = 0; it < 8; ++it) {
        int idx = it * 256 + t;
        int nd = idx >> 4, s = idx & 15;
        float4 v0 = make_float4(0, 0, 0, 0), v1 = v0;
        if (nd < nrem) {
            const float4* px = (const float4*)(x + (size_t)(node0 + nd) * 128 + s * 8);
            v0 = px[0]; v1 = px[1];
        }
        uint4 w;
        w.x = pkbf(v0.x, v0.y); w.y = pkbf(v0.z, v0.w);
        w.z = pkbf(v1.x, v1.y); w.w = pkbf(v1.z, v1.w);
        LB[nd * 16 + (s ^ (nd & 7))] = w;
        LW[idx] = WtE[idx];
    }
    __syncthreads();

    const char* lb = (const char*)LB;
    const char* lw = (const char*)LW;

    // GEMM1: h^T = encW^T x^T  (D rows = h-cols, cols = nodes)
    f32x16 a0 = {}, a1 = {}, a2 = {}, a3 = {};
    #pragma unroll
    for (int r = 0; r < 16; ++r) {
        int rr = (r & 3) + 8 * (r >> 2) + 4 * hh;
        a0[r] = enc_b[rr];      a1[r] = enc_b[32 + rr];
        a2[r] = enc_b[64 + rr]; a3[r] = enc_b[96 + rr];
    }
    #pragma unroll
    for (int ks = 0; ks < 8; ++ks) {
        int so = ((ks * 2 + hh) ^ sw7) << 4;
        s16x8 bf = *(const s16x8*)(lb + nloc * 256 + so);
        s16x8 w0 = *(const s16x8*)(lw + l31 * 256 + so);
        s16x8 w1 = *(const s16x8*)(lw + 8192 + l31 * 256 + so);
        s16x8 w2 = *(const s16x8*)(lw + 16384 + l31 * 256 + so);
        s16x8 w3 = *(const s16x8*)(lw + 24576 + l31 * 256 + so);
        a0 = __builtin_amdgcn_mfma_f32_32x32x16_bf16(w0, bf, a0, 0, 0, 0);
        a1 = __builtin_amdgcn_mfma_f32_32x32x16_bf16(w1, bf, a1, 0, 0, 0);
        a2 = __builtin_amdgcn_mfma_f32_32x32x16_bf16(w2, bf, a2, 0, 0, 0);
        a3 = __builtin_amdgcn_mfma_f32_32x32x16_bf16(w3, bf, a3, 0, 0, 0);
    }

    // h^T -> in-register bf16 fragments (k = h-col)
    uint4 hf[8];
    BUILDF(hf[0], a0, 0, hh); BUILDF(hf[1], a0, 1, hh);
    BUILDF(hf[2], a1, 0, hh); BUILDF(hf[3], a1, 1, hh);
    BUILDF(hf[4], a2, 0, hh); BUILDF(hf[5], a2, 1, hh);
    BUILDF(hf[6], a3, 0, hh); BUILDF(hf[7], a3, 1, hh);

    // h rows -> global (pre-swizzled bf16 rows)
    if (nloc < nrem) {
        const size_t rb = (size_t)(node0 + nloc) * 16;
        #pragma unroll
        for (int f = 0; f < 8; ++f) {
            int g = 2 * f + hh;
            h_g[rb + (g ^ sw7)] = hf[f];
        }
    }

    __syncthreads();   // done reading WtE
    #pragma unroll
    for (int it = 0; it < 8; ++it) LW[it * 256 + t] = WtM[it * 256 + t];
    {   // sigWt (8KB) into LS
        uint4* LSu = (uint4*)LS;
        LSu[t] = WtS[t]; LSu[256 + t] = WtS[256 + t];
    }
    __syncthreads();

    // GEMM2: msg^T = msgW^T h^T  (B-operand = in-reg h frags)
    f32x16 m0 = {}, m1 = {}, m2 = {}, m3 = {};
    #pragma unroll
    for (int r = 0; r < 16; ++r) {
        int rr = (r & 3) + 8 * (r >> 2) + 4 * hh;
        m0[r] = msg_b[rr];      m1[r] = msg_b[32 + rr];
        m2[r] = msg_b[64 + rr]; m3[r] = msg_b[96 + rr];
    }
    #pragma unroll
    for (int ks = 0; ks < 8; ++ks) {
        int so = ((ks * 2 + hh) ^ sw7) << 4;
        U16B hb; hb.u = hf[ks];
        s16x8 w0 = *(const s16x8*)(lw + l31 * 256 + so);
        s16x8 w1 = *(const s16x8*)(lw + 8192 + l31 * 256 + so);
        s16x8 w2 = *(const s16x8*)(lw + 16384 + l31 * 256 + so);
        s16x8 w3 = *(const s16x8*)(lw + 24576 + l31 * 256 + so);
        m0 = __builtin_amdgcn_mfma_f32_32x32x16_bf16(w0, hb.s, m0, 0, 0, 0);
        m1 = __builtin_amdgcn_mfma_f32_32x32x16_bf16(w1, hb.s, m1, 0, 0, 0);
        m2 = __builtin_amdgcn_mfma_f32_32x32x16_bf16(w2, hb.s, m2, 0, 0, 0);
        m3 = __builtin_amdgcn_mfma_f32_32x32x16_bf16(w3, hb.s, m3, 0, 0, 0);
    }
    {   // relu + store msg rows
        uint4 mf[8];
        BUILDR(mf[0], m0, 0, hh); BUILDR(mf[1], m0, 1, hh);
        BUILDR(mf[2], m1, 0, hh); BUILDR(mf[3], m1, 1, hh);
        BUILDR(mf[4], m2, 0, hh); BUILDR(mf[5], m2, 1, hh);
        BUILDR(mf[6], m3, 0, hh); BUILDR(mf[7], m3, 1, hh);
        if (nloc < nrem) {
            const size_t rb = (size_t)(node0 + nloc) * 16;
            #pragma unroll
            for (int f = 0; f < 8; ++f) {
                int g = 2 * f + hh;
                msg_g[rb + (g ^ sw7)] = mf[f];
            }
        }
    }

    // GEMM3: sig^T = sigW^T h^T  (rows 16..31 of sigWt are zero)
    f32x16 sg = {};
    #pragma unroll
    for (int r = 0; r < 8; ++r) {
        int rr = (r & 3) + 8 * (r >> 2) + 4 * hh;   // < 16
        sg[r] = sig_b[rr];
    }
    const char* lsw = (const char*)LS;
    #pragma unroll
    for (int ks = 0; ks < 8; ++ks) {
        int so = ((ks * 2 + hh) ^ sw7) << 4;
        s16x8 aw = *(const s16x8*)(lsw + l31 * 256 + so);
        U16B hb; hb.u = hf[ks];
        sg = __builtin_amdgcn_mfma_f32_32x32x16_bf16(aw, hb.s, sg, 0, 0, 0);
    }
    float ss = 0.f;
    #pragma unroll
    for (int r = 0; r < 8; ++r) ss += sg[r] * sg[r];
    ss += __shfl_xor(ss, 32);
    float inv = 1.0f / fmaxf(sqrtf(ss), 1e-12f);
    __syncthreads();   // all sigWt reads done before funnel overwrite
    #pragma unroll
    for (int r = 0; r < 8; ++r) {
        int sc = (r & 3) + 8 * (r >> 2) + 4 * hh;
        LS[nloc * 17 + sc] = sg[r] * inv;
    }
    __syncthreads();
    // sig rows -> global as bf16 pairs (8 u32 per node)
    #pragma unroll
    for (int it = 0; it < 4; ++it) {
        int idx = it * 256 + t;           // 1024 = 128 nodes x 8 u32
        int nd = idx >> 3, c2 = idx & 7;
        if (nd < nrem)
            sig_bf[(size_t)(node0 + nd) * 8 + c2] =
                pkbf(LS[nd * 17 + 2 * c2], LS[nd * 17 + 2 * c2 + 1]);
    }
}

// ---------------------------------------------------------------------------
// decode (MFMA): out = relu([h|comm]@agg_w+b) @ dec_w + b
// Block = 64 nodes, 4 waves: wave = (node half) x (64 col half).
// ---------------------------------------------------------------------------
__global__ __launch_bounds__(256) void k_decode_m(
    const uint4* __restrict__ h_g, const uint4* __restrict__ comm,
    const uint4* __restrict__ WtA0, const uint4* __restrict__ WtA1,
    const uint4* __restrict__ WtD,
    const float* __restrict__ agg_b, const float* __restrict__ dec_b,
    float* __restrict__ out)
{
    __shared__ uint4 LB[2048];   // Bcat [64][32 granules]; later Lcomb [64][16]
    __shared__ uint4 LW[2048];

    const int t = threadIdx.x;
    const int node0 = blockIdx.x * 64;
    int nrem = N_NODES - node0; if (nrem > 64) nrem = 64;
    const int lane = t & 63, wid = t >> 6;
    const int l31 = lane & 31, hh = lane >> 5;
    const int ng = wid & 1, cp = wid >> 1;
    const int nloc = ng * 32 + l31;
    const int sw7 = l31 & 7;

    // stage Bcat = [h | comm] bf16 (both pre-swizzled: linear copy)
    #pragma unroll
    for (int it = 0; it < 8; ++it) {
        int idx = it * 256 + t;
        int nd = idx >> 5, g = idx & 31;
        uint4 v = make_uint4(0, 0, 0, 0);
        if (nd < nrem)
            v = (g < 16) ? h_g[(size_t)(node0 + nd) * 16 + g]
                         : comm[(size_t)(node0 + nd) * 16 + (g - 16)];
        LB[nd * 32 + g] = v;
        LW[idx] = WtA0[idx];
    }
    __syncthreads();

    const char* lb = (const char*)LB;
    const char* lw = (const char*)LW;

    // GEMM-A: combined^T = aggW^T [h|comm]^T  (K = 256, staged in halves)
    f32x16 c0 = {}, c1 = {};
    #pragma unroll
    for (int r = 0; r < 16; ++r) {
        int rr = (r & 3) + 8 * (r >> 2) + 4 * hh;
        c0[r] = agg_b[cp * 64 + rr];
        c1[r] = agg_b[cp * 64 + 32 + rr];
    }
    #pragma unroll
    for (int ks = 0; ks < 8; ++ks) {
        int so = ((ks * 2 + hh) ^ sw7) << 4;
        s16x8 bf = *(const s16x8*)(lb + nloc * 512 + so);
        s16x8 w0 = *(const s16x8*)(lw + (cp * 64 + l31) * 256 + so);
        s16x8 w1 = *(const s16x8*)(lw + (cp * 64 + 32 + l31) * 256 + so);
        c0 = __builtin_amdgcn_mfma_f32_32x32x16_bf16(w0, bf, c0, 0, 0, 0);
        c1 = __builtin_amdgcn_mfma_f32_32x32x16_bf16(w1, bf, c1, 0, 0, 0);
    }
    __syncthreads();
    #pragma unroll
    for (int it = 0; it < 8; ++it) LW[it * 256 + t] = WtA1[it * 256 + t];
    __syncthreads();
    #pragma unroll
    for (int ks = 8; ks < 16; ++ks) {
        int so = ((ks * 2 + hh) ^ sw7) << 4;            // bit4 kept: comm half
        int so2 = (((ks - 8) * 2 + hh) ^ sw7) << 4;
        s16x8 bf = *(const s16x8*)(lb + nloc * 512 + so);
        s16x8 w0 = *(const s16x8*)(lw + (cp * 64 + l31) * 256 + so2);
        s16x8 w1 = *(const s16x8*)(lw + (cp * 64 + 32 + l31) * 256 + so2);
        c0 = __builtin_amdgcn_mfma_f32_32x32x16_bf16(w0, bf, c0, 0, 0, 0);
        c1 = __builtin_amdgcn_mfma_f32_32x32x16_bf16(w1, bf, c1, 0, 0, 0);
    }
    __syncthreads();   // all Bcat / WtA1 reads done

    // relu + build combined fragments; exchange across waves via LB (Lcomb)
    {
        uint4 cf[4];
        BUILDR(cf[0], c0, 0, hh); BUILDR(cf[1], c0, 1, hh);
        BUILDR(cf[2], c1, 0, hh); BUILDR(cf[3], c1, 1, hh);
        #pragma unroll
        for (int f = 0; f < 4; ++f) {
            int g = (cp * 4 + f) * 2 + hh;
            LB[nloc * 16 + (g ^ sw7)] = cf[f];
        }
    }
    #pragma unroll
    for (int it = 0; it < 8; ++it) LW[it * 256 + t] = WtD[it * 256 + t];
    __syncthreads();

    // GEMM-B: out = combined @ dec_w  (A = in-LDS combined frags, lane = outcol)
    f32x16 o0 = {}, o1 = {};
    {
        float b0 = dec_b[cp * 64 + l31], b1 = dec_b[cp * 64 + 32 + l31];
        #pragma unroll
        for (int r = 0; r < 16; ++r) { o0[r] = b0; o1[r] = b1; }
    }
    #pragma unroll
    for (int ks = 0; ks < 8; ++ks) {
        int so = ((ks * 2 + hh) ^ sw7) << 4;
        s16x8 af = *(const s16x8*)(lb + nloc * 256 + so);
        s16x8 w0 = *(const s16x8*)(lw + (cp * 64 + l31) * 256 + so);
        s16x8 w1 = *(const s16x8*)(lw + (cp * 64 + 32 + l31) * 256 + so);
        o0 = __builtin_amdgcn_mfma_f32_32x32x16_bf16(af, w0, o0, 0, 0, 0);
        o1 = __builtin_amdgcn_mfma_f32_32x32x16_bf16(af, w1, o1, 0, 0, 0);
    }
    #pragma unroll
    for (int r = 0; r < 16; ++r) {
        int nd = ng * 32 + (r & 3) + 8 * (r >> 2) + 4 * hh;
        if (nd < nrem) {
            float* row = out + (size_t)(node0 + nd) * 128 + cp * 64;
            row[l31]      = o0[r];
            row[32 + l31] = o1[r];
        }
    }
}

// ---------------------------------------------------------------------------
// aggr: wave per node. Lane l computes e_l = exp(sig[node].sig[dst_l]) in
// parallel (cnt <= CAP = 64 lanes); den via shfl_xor reduce; PV loop
// broadcasts (e_k, d_k) via shfl. msg/comm rows pre-swizzled bf16.
// ---------------------------------------------------------------------------
__global__ __launch_bounds__(256) void k_aggr_s(
    const int* __restrict__ counts, const u32* __restrict__ bucket,
    const u32* __restrict__ sig_bf,
    const char* __restrict__ msg_g, char* __restrict__ comm)
{
    const int wave = threadIdx.x >> 6;
    const int lane = threadIdx.x & 63;
    int node = blockIdx.x * 4 + wave;
    if (node >= N_NODES) return;
    const int cnt = counts[node];
    const u32* bk = bucket + (size_t)node * CAP;

    // lane-parallel score phase
    int dl = (lane < cnt) ? (int)bk[lane] : 0;
    const uint4* pn = (const uint4*)(sig_bf + (size_t)node * 8);
    uint4 na = pn[0], nb = pn[1];
    float el = 0.f;
    if (lane < cnt) {
        const uint4* pd = (const uint4*)(sig_bf + (size_t)dl * 8);
        uint4 da = pd[0], db = pd[1];
        float dot = dotpair(na.x, da.x) + dotpair(na.y, da.y)
                  + dotpair(na.z, da.z) + dotpair(na.w, da.w)
                  + dotpair(nb.x, db.x) + dotpair(nb.y, db.y)
                  + dotpair(nb.z, db.z) + dotpair(nb.w, db.w);
        el = __expf(dot);   // |dot|<=1 (unit sigs): segment_max elision exact
    }
    float den = el;
    #pragma unroll
    for (int o = 1; o < 64; o <<= 1) den += __shfl_xor(den, o);

    // PV phase: lane = 2 dims
    const int lo4 = 4 * lane;
    float ax = 0.f, ay = 0.f;
    int k = 0;
    for (; k + 4 <= cnt; k += 4) {
        float e0 = __shfl(el, k),     e1 = __shfl(el, k + 1);
        float e2 = __shfl(el, k + 2), e3 = __shfl(el, k + 3);
        int d0 = __shfl(dl, k),     d1 = __shfl(dl, k + 1);
        int d2 = __shfl(dl, k + 2), d3 = __shfl(dl, k + 3);
        u32 m0 = *(const u32*)(msg_g + (size_t)d0 * 256 + (lo4 ^ ((d0 & 7) << 4)));
        u32 m1 = *(const u32*)(msg_g + (size_t)d1 * 256 + (lo4 ^ ((d1 & 7) << 4)));
        u32 m2 = *(const u32*)(msg_g + (size_t)d2 * 256 + (lo4 ^ ((d2 & 7) << 4)));
        u32 m3 = *(const u32*)(msg_g + (size_t)d3 * 256 + (lo4 ^ ((d3 & 7) << 4)));
        ax += e0 * bf2f(m0 & 0xFFFF) + e1 * bf2f(m1 & 0xFFFF)
            + e2 * bf2f(m2 & 0xFFFF) + e3 * bf2f(m3 & 0xFFFF);
        ay += e0 * bf2f(m0 >> 16) + e1 * bf2f(m1 >> 16)
            + e2 * bf2f(m2 >> 16) + e3 * bf2f(m3 >> 16);
    }
    for (; k < cnt; ++k) {
        float ev = __shfl(el, k);
        int dn = __shfl(dl, k);
        u32 m = *(const u32*)(msg_g + (size_t)dn * 256 + (lo4 ^ ((dn & 7) << 4)));
        ax += ev * bf2f(m & 0xFFFF);
        ay += ev * bf2f(m >> 16);
    }
    float inv = (den > 0.f) ? (1.0f / den) : 0.f;
    *(u32*)(comm + (size_t)node * 256 + (lo4 ^ ((node & 7) << 4))) = pkbf(ax * inv, ay * inv);
}

// ---------------------------------------------------------------------------
extern "C" void kernel_launch(void* const* d_in, const int* in_sizes, int n_in,
                              void* d_out, int out_size, void* d_ws, size_t ws_size,
                              hipStream_t stream)
{
    const float* x     = (const float*)d_in[0];
    const int*   ei    = (const int*)  d_in[1];
    const float* enc_w = (const float*)d_in[2];
    const float* enc_b = (const float*)d_in[3];
    const float* sig_w = (const float*)d_in[4];
    const float* sig_b = (const float*)d_in[5];
    const float* msg_w = (const float*)d_in[6];
    const float* msg_b = (const float*)d_in[7];
    const float* agg_w = (const float*)d_in[8];
    const float* agg_b = (const float*)d_in[9];
    const float* dec_w = (const float*)d_in[10];
    const float* dec_b = (const float*)d_in[11];
    float* out = (float*)d_out;

    const int* src = ei;            // edge_index[0]
    const int* dst = ei + N_EDGES;  // edge_index[1]

    // workspace layout (bytes), ~52 MB
    char* p = (char*)d_ws;
    uint4* h_g   = (uint4*)p;  p += (size_t)N_NODES * 256;  // bf16 rows, swizzled
    uint4* msg_g = (uint4*)p;  p += (size_t)N_NODES * 256;
    uint4* comm  = (uint4*)p;  p += (size_t)N_NODES * 256;
    u32*   sig_bf = (u32*)p;   p += (size_t)N_NODES * 32;   // bf16 sig rows
    u32*   bucket = (u32*)p;   p += (size_t)N_NODES * CAP * 4;
    int*   counts = (int*)p;   p += (size_t)N_NODES * 4;
    uint4* WtE  = (uint4*)p; p += 32768;
    uint4* WtM  = (uint4*)p; p += 32768;
    uint4* WtD  = (uint4*)p; p += 32768;
    uint4* WtA0 = (uint4*)p; p += 32768;
    uint4* WtA1 = (uint4*)p; p += 32768;
    uint4* WtS  = (uint4*)p; p += 8192;

    hipMemsetAsync(counts, 0, (size_t)N_NODES * sizeof(int), stream);

    k_prep<<<42, 256, 0, stream>>>(enc_w, msg_w, sig_w, agg_w, dec_w,
                                   WtE, WtM, WtD, WtA0, WtA1, WtS);
    k_enc_scat<<<NBE + NBS, 256, 0, stream>>>(
        x, WtE, WtM, WtS, enc_b, sig_b, msg_b, h_g, sig_bf, msg_g,
        src, dst, counts, bucket);
    k_aggr_s<<<(N_NODES + 3) / 4, 256, 0, stream>>>(
        counts, bucket, sig_bf, (const char*)msg_g, (char*)comm);
    k_decode_m<<<(N_NODES + 63) / 64, 256, 0, stream>>>(
        h_g, comm, WtA0, WtA1, WtD, agg_b, dec_b, out);
}

// Round 12
// 120.426 us; speedup vs baseline: 1.1981x; 1.1981x over previous
//
#include <hip/hip_runtime.h>
#include <math.h>

#define N_NODES 50000
#define N_EDGES 800000
#define CAP 64     // bucket capacity per node (max degree <= 64, validated r7-r11)
#define NRANGE 391 // ceil(N_NODES/128) ranges of 128 nodes
#define PCAP 2560  // part capacity per range (mean 2046, +11 sigma)
#define EPBA 8192  // edges per partA block
#define NBA 98     // ceil(N_EDGES/EPBA)

typedef __attribute__((ext_vector_type(8)))  short s16x8;   // 8 bf16 (4 VGPR)
typedef __attribute__((ext_vector_type(16))) float f32x16;  // MFMA acc
typedef unsigned int u32;
typedef unsigned short u16;

union U16B { uint4 u; s16x8 s; };

// f32 -> bf16 bits, round-to-nearest-even
__device__ __forceinline__ u32 bfr(float f) {
    u32 u = __float_as_uint(f);
    return (u + 0x7FFFu + ((u >> 16) & 1u)) >> 16;
}
__device__ __forceinline__ u32 pkbf(float a, float b) { return bfr(a) | (bfr(b) << 16); }
__device__ __forceinline__ float bf2f(u32 b) { return __uint_as_float(b << 16); }
// dot of a bf16x2 pair against another
__device__ __forceinline__ float dotpair(u32 a, u32 b) {
    return bf2f(a & 0xFFFFu) * bf2f(b & 0xFFFFu) + bf2f(a >> 16) * bf2f(b >> 16);
}

// Build an MFMA input frag (lane-dim = D-col, k = 8*(lane>>5)+e) from 8 f32
// D-regs of a 32x32x16 accumulator (rows (r&3)+8*(r>>2)+4*hh), via bf16 pack
// + half-wave exchange. d8 must be compile-time indexed by caller.
__device__ __forceinline__ uint4 buildfrag(const float* d8, int hh) {
    u32 P = pkbf(d8[0], d8[1]), Q = pkbf(d8[2], d8[3]);
    u32 R = pkbf(d8[4], d8[5]), S = pkbf(d8[6], d8[7]);
    u32 sP = (u32)__shfl_xor((int)P, 32);
    u32 sQ = (u32)__shfl_xor((int)Q, 32);
    u32 sR = (u32)__shfl_xor((int)R, 32);
    u32 sS = (u32)__shfl_xor((int)S, 32);
    uint4 f;
    f.x = hh ? sR : P;  f.y = hh ? sS : Q;
    f.z = hh ? R : sP;  f.w = hh ? S : sQ;
    return f;
}
#define BUILDF(OUT, ACC, Q, HH) do { \
    float _td[8]; \
    _Pragma("unroll") for (int _z = 0; _z < 8; ++_z) _td[_z] = (ACC)[(Q)*8 + _z]; \
    (OUT) = buildfrag(_td, HH); } while (0)
#define BUILDR(OUT, ACC, Q, HH) do { \
    float _td[8]; \
    _Pragma("unroll") for (int _z = 0; _z < 8; ++_z) _td[_z] = fmaxf((ACC)[(Q)*8 + _z], 0.f); \
    (OUT) = buildfrag(_td, HH); } while (0)

// ---------------------------------------------------------------------------
// prep: weights -> bf16, transposed [col][k] rows (256B), granule-XOR swizzled
// ---------------------------------------------------------------------------
__global__ __launch_bounds__(256) void k_prep(
    const float* __restrict__ enc_w, const float* __restrict__ msg_w,
    const float* __restrict__ sig_w, const float* __restrict__ agg_w,
    const float* __restrict__ dec_w,
    uint4* __restrict__ WtE, uint4* __restrict__ WtM, uint4* __restrict__ WtD,
    uint4* __restrict__ WtA0, uint4* __restrict__ WtA1, uint4* __restrict__ WtS)
{
    int gid = blockIdx.x * 256 + threadIdx.x;
    if (gid < 10240) {
        int m = gid >> 11, r = gid & 2047;
        int col = r >> 4, s = r & 15;
        const float* W; uint4* D; int kb = 0;
        if      (m == 0) { W = enc_w; D = WtE; }
        else if (m == 1) { W = msg_w; D = WtM; }
        else if (m == 2) { W = dec_w; D = WtD; }
        else if (m == 3) { W = agg_w; D = WtA0; }
        else             { W = agg_w; D = WtA1; kb = 128; }
        float v[8];
        #pragma unroll
        for (int j = 0; j < 8; ++j) v[j] = W[(size_t)(kb + s * 8 + j) * 128 + col];
        uint4 w;
        w.x = pkbf(v[0], v[1]); w.y = pkbf(v[2], v[3]);
        w.z = pkbf(v[4], v[5]); w.w = pkbf(v[6], v[7]);
        D[col * 16 + (s ^ (col & 7))] = w;
    } else if (gid < 10752) {
        int r = gid - 10240;
        int row = r >> 4, s = r & 15;
        float v[8];
        #pragma unroll
        for (int j = 0; j < 8; ++j)
            v[j] = (row < 16) ? sig_w[(size_t)(s * 8 + j) * 16 + row] : 0.0f;
        uint4 w;
        w.x = pkbf(v[0], v[1]); w.y = pkbf(v[2], v[3]);
        w.z = pkbf(v[4], v[5]); w.w = pkbf(v[6], v[7]);
        WtS[row * 16 + (s ^ (row & 7))] = w;
    }
}

// ---------------------------------------------------------------------------
// encode (MFMA): h = x@enc_w+b ; msg = relu(h@msg_w+b) ; sig = l2n(h@sig_w+b)
// Block = 128 nodes, 4 waves x 32 nodes. All GEMMs computed transposed
// (D = W^T x^T) so lane-dim = node; h^T fragments stay in registers.
// ---------------------------------------------------------------------------
__global__ __launch_bounds__(256) void k_encode_m(
    const float* __restrict__ x,
    const uint4* __restrict__ WtE, const uint4* __restrict__ WtM,
    const uint4* __restrict__ WtS,
    const float* __restrict__ enc_b, const float* __restrict__ sig_b,
    const float* __restrict__ msg_b,
    uint4* __restrict__ h_g, u32* __restrict__ sig_bf, uint4* __restrict__ msg_g)
{
    __shared__ uint4 LB[2048];   // x tile bf16 [128 nodes][16 granules]
    __shared__ uint4 LW[2048];   // weight tile [128 cols][16 granules]
    __shared__ float LS[2176];   // sigWt (8KB) then sig funnel (8.7KB)

    const int t = threadIdx.x;
    const int node0 = blockIdx.x * 128;
    int nrem = N_NODES - node0; if (nrem > 128) nrem = 128;
    const int lane = t & 63, wid = t >> 6;
    const int l31 = lane & 31, hh = lane >> 5;
    const int nloc = wid * 32 + l31;
    const int sw7 = l31 & 7;

    // stage x (f32->bf16, swizzled) + enc weights
    #pragma unroll
    for (int it = 0; it < 8; ++it) {
        int idx = it * 256 + t;
        int nd = idx >> 4, s = idx & 15;
        float4 v0 = make_float4(0, 0, 0, 0), v1 = v0;
        if (nd < nrem) {
            const float4* px = (const float4*)(x + (size_t)(node0 + nd) * 128 + s * 8);
            v0 = px[0]; v1 = px[1];
        }
        uint4 w;
        w.x = pkbf(v0.x, v0.y); w.y = pkbf(v0.z, v0.w);
        w.z = pkbf(v1.x, v1.y); w.w = pkbf(v1.z, v1.w);
        LB[nd * 16 + (s ^ (nd & 7))] = w;
        LW[idx] = WtE[idx];
    }
    __syncthreads();

    const char* lb = (const char*)LB;
    const char* lw = (const char*)LW;

    // GEMM1: h^T = encW^T x^T  (D rows = h-cols, cols = nodes)
    f32x16 a0 = {}, a1 = {}, a2 = {}, a3 = {};
    #pragma unroll
    for (int r = 0; r < 16; ++r) {
        int rr = (r & 3) + 8 * (r >> 2) + 4 * hh;
        a0[r] = enc_b[rr];      a1[r] = enc_b[32 + rr];
        a2[r] = enc_b[64 + rr]; a3[r] = enc_b[96 + rr];
    }
    #pragma unroll
    for (int ks = 0; ks < 8; ++ks) {
        int so = ((ks * 2 + hh) ^ sw7) << 4;
        s16x8 bf = *(const s16x8*)(lb + nloc * 256 + so);
        s16x8 w0 = *(const s16x8*)(lw + l31 * 256 + so);
        s16x8 w1 = *(const s16x8*)(lw + 8192 + l31 * 256 + so);
        s16x8 w2 = *(const s16x8*)(lw + 16384 + l31 * 256 + so);
        s16x8 w3 = *(const s16x8*)(lw + 24576 + l31 * 256 + so);
        a0 = __builtin_amdgcn_mfma_f32_32x32x16_bf16(w0, bf, a0, 0, 0, 0);
        a1 = __builtin_amdgcn_mfma_f32_32x32x16_bf16(w1, bf, a1, 0, 0, 0);
        a2 = __builtin_amdgcn_mfma_f32_32x32x16_bf16(w2, bf, a2, 0, 0, 0);
        a3 = __builtin_amdgcn_mfma_f32_32x32x16_bf16(w3, bf, a3, 0, 0, 0);
    }

    // h^T -> in-register bf16 fragments (k = h-col)
    uint4 hf[8];
    BUILDF(hf[0], a0, 0, hh); BUILDF(hf[1], a0, 1, hh);
    BUILDF(hf[2], a1, 0, hh); BUILDF(hf[3], a1, 1, hh);
    BUILDF(hf[4], a2, 0, hh); BUILDF(hf[5], a2, 1, hh);
    BUILDF(hf[6], a3, 0, hh); BUILDF(hf[7], a3, 1, hh);

    // h rows -> global (pre-swizzled bf16 rows)
    if (nloc < nrem) {
        const size_t rb = (size_t)(node0 + nloc) * 16;
        #pragma unroll
        for (int f = 0; f < 8; ++f) {
            int g = 2 * f + hh;
            h_g[rb + (g ^ sw7)] = hf[f];
        }
    }

    __syncthreads();   // done reading WtE
    #pragma unroll
    for (int it = 0; it < 8; ++it) LW[it * 256 + t] = WtM[it * 256 + t];
    {   // sigWt (8KB) into LS
        uint4* LSu = (uint4*)LS;
        LSu[t] = WtS[t]; LSu[256 + t] = WtS[256 + t];
    }
    __syncthreads();

    // GEMM2: msg^T = msgW^T h^T  (B-operand = in-reg h frags)
    f32x16 m0 = {}, m1 = {}, m2 = {}, m3 = {};
    #pragma unroll
    for (int r = 0; r < 16; ++r) {
        int rr = (r & 3) + 8 * (r >> 2) + 4 * hh;
        m0[r] = msg_b[rr];      m1[r] = msg_b[32 + rr];
        m2[r] = msg_b[64 + rr]; m3[r] = msg_b[96 + rr];
    }
    #pragma unroll
    for (int ks = 0; ks < 8; ++ks) {
        int so = ((ks * 2 + hh) ^ sw7) << 4;
        U16B hb; hb.u = hf[ks];
        s16x8 w0 = *(const s16x8*)(lw + l31 * 256 + so);
        s16x8 w1 = *(const s16x8*)(lw + 8192 + l31 * 256 + so);
        s16x8 w2 = *(const s16x8*)(lw + 16384 + l31 * 256 + so);
        s16x8 w3 = *(const s16x8*)(lw + 24576 + l31 * 256 + so);
        m0 = __builtin_amdgcn_mfma_f32_32x32x16_bf16(w0, hb.s, m0, 0, 0, 0);
        m1 = __builtin_amdgcn_mfma_f32_32x32x16_bf16(w1, hb.s, m1, 0, 0, 0);
        m2 = __builtin_amdgcn_mfma_f32_32x32x16_bf16(w2, hb.s, m2, 0, 0, 0);
        m3 = __builtin_amdgcn_mfma_f32_32x32x16_bf16(w3, hb.s, m3, 0, 0, 0);
    }
    {   // relu + store msg rows
        uint4 mf[8];
        BUILDR(mf[0], m0, 0, hh); BUILDR(mf[1], m0, 1, hh);
        BUILDR(mf[2], m1, 0, hh); BUILDR(mf[3], m1, 1, hh);
        BUILDR(mf[4], m2, 0, hh); BUILDR(mf[5], m2, 1, hh);
        BUILDR(mf[6], m3, 0, hh); BUILDR(mf[7], m3, 1, hh);
        if (nloc < nrem) {
            const size_t rb = (size_t)(node0 + nloc) * 16;
            #pragma unroll
            for (int f = 0; f < 8; ++f) {
                int g = 2 * f + hh;
                msg_g[rb + (g ^ sw7)] = mf[f];
            }
        }
    }

    // GEMM3: sig^T = sigW^T h^T  (rows 16..31 of sigWt are zero)
    f32x16 sg = {};
    #pragma unroll
    for (int r = 0; r < 8; ++r) {
        int rr = (r & 3) + 8 * (r >> 2) + 4 * hh;   // < 16
        sg[r] = sig_b[rr];
    }
    const char* lsw = (const char*)LS;
    #pragma unroll
    for (int ks = 0; ks < 8; ++ks) {
        int so = ((ks * 2 + hh) ^ sw7) << 4;
        s16x8 aw = *(const s16x8*)(lsw + l31 * 256 + so);
        U16B hb; hb.u = hf[ks];
        sg = __builtin_amdgcn_mfma_f32_32x32x16_bf16(aw, hb.s, sg, 0, 0, 0);
    }
    float ss = 0.f;
    #pragma unroll
    for (int r = 0; r < 8; ++r) ss += sg[r] * sg[r];
    ss += __shfl_xor(ss, 32);
    float inv = 1.0f / fmaxf(sqrtf(ss), 1e-12f);
    __syncthreads();   // all sigWt reads done before funnel overwrite
    #pragma unroll
    for (int r = 0; r < 8; ++r) {
        int sc = (r & 3) + 8 * (r >> 2) + 4 * hh;
        LS[nloc * 17 + sc] = sg[r] * inv;
    }
    __syncthreads();
    // sig rows -> global as bf16 pairs (8 u32 per node)
    #pragma unroll
    for (int it = 0; it < 4; ++it) {
        int idx = it * 256 + t;           // 1024 = 128 nodes x 8 u32
        int nd = idx >> 3, c2 = idx & 7;
        if (nd < nrem)
            sig_bf[(size_t)(node0 + nd) * 8 + c2] =
                pkbf(LS[nd * 17 + 2 * c2], LS[nd * 17 + 2 * c2 + 1]);
    }
}

// ---------------------------------------------------------------------------
// decode (MFMA): out = relu([h|comm]@agg_w+b) @ dec_w + b
// Block = 64 nodes, 4 waves: wave = (node half) x (64 col half).
// ---------------------------------------------------------------------------
__global__ __launch_bounds__(256) void k_decode_m(
    const uint4* __restrict__ h_g, const uint4* __restrict__ comm,
    const uint4* __restrict__ WtA0, const uint4* __restrict__ WtA1,
    const uint4* __restrict__ WtD,
    const float* __restrict__ agg_b, const float* __restrict__ dec_b,
    float* __restrict__ out)
{
    __shared__ uint4 LB[2048];   // Bcat [64][32 granules]; later Lcomb [64][16]
    __shared__ uint4 LW[2048];

    const int t = threadIdx.x;
    const int node0 = blockIdx.x * 64;
    int nrem = N_NODES - node0; if (nrem > 64) nrem = 64;
    const int lane = t & 63, wid = t >> 6;
    const int l31 = lane & 31, hh = lane >> 5;
    const int ng = wid & 1, cp = wid >> 1;
    const int nloc = ng * 32 + l31;
    const int sw7 = l31 & 7;

    // stage Bcat = [h | comm] bf16 (both pre-swizzled: linear copy)
    #pragma unroll
    for (int it = 0; it < 8; ++it) {
        int idx = it * 256 + t;
        int nd = idx >> 5, g = idx & 31;
        uint4 v = make_uint4(0, 0, 0, 0);
        if (nd < nrem)
            v = (g < 16) ? h_g[(size_t)(node0 + nd) * 16 + g]
                         : comm[(size_t)(node0 + nd) * 16 + (g - 16)];
        LB[nd * 32 + g] = v;
        LW[idx] = WtA0[idx];
    }
    __syncthreads();

    const char* lb = (const char*)LB;
    const char* lw = (const char*)LW;

    // GEMM-A: combined^T = aggW^T [h|comm]^T  (K = 256, staged in halves)
    f32x16 c0 = {}, c1 = {};
    #pragma unroll
    for (int r = 0; r < 16; ++r) {
        int rr = (r & 3) + 8 * (r >> 2) + 4 * hh;
        c0[r] = agg_b[cp * 64 + rr];
        c1[r] = agg_b[cp * 64 + 32 + rr];
    }
    #pragma unroll
    for (int ks = 0; ks < 8; ++ks) {
        int so = ((ks * 2 + hh) ^ sw7) << 4;
        s16x8 bf = *(const s16x8*)(lb + nloc * 512 + so);
        s16x8 w0 = *(const s16x8*)(lw + (cp * 64 + l31) * 256 + so);
        s16x8 w1 = *(const s16x8*)(lw + (cp * 64 + 32 + l31) * 256 + so);
        c0 = __builtin_amdgcn_mfma_f32_32x32x16_bf16(w0, bf, c0, 0, 0, 0);
        c1 = __builtin_amdgcn_mfma_f32_32x32x16_bf16(w1, bf, c1, 0, 0, 0);
    }
    __syncthreads();
    #pragma unroll
    for (int it = 0; it < 8; ++it) LW[it * 256 + t] = WtA1[it * 256 + t];
    __syncthreads();
    #pragma unroll
    for (int ks = 8; ks < 16; ++ks) {
        int so = ((ks * 2 + hh) ^ sw7) << 4;            // bit4 kept: comm half
        int so2 = (((ks - 8) * 2 + hh) ^ sw7) << 4;
        s16x8 bf = *(const s16x8*)(lb + nloc * 512 + so);
        s16x8 w0 = *(const s16x8*)(lw + (cp * 64 + l31) * 256 + so2);
        s16x8 w1 = *(const s16x8*)(lw + (cp * 64 + 32 + l31) * 256 + so2);
        c0 = __builtin_amdgcn_mfma_f32_32x32x16_bf16(w0, bf, c0, 0, 0, 0);
        c1 = __builtin_amdgcn_mfma_f32_32x32x16_bf16(w1, bf, c1, 0, 0, 0);
    }
    __syncthreads();   // all Bcat / WtA1 reads done

    // relu + build combined fragments; exchange across waves via LB (Lcomb)
    {
        uint4 cf[4];
        BUILDR(cf[0], c0, 0, hh); BUILDR(cf[1], c0, 1, hh);
        BUILDR(cf[2], c1, 0, hh); BUILDR(cf[3], c1, 1, hh);
        #pragma unroll
        for (int f = 0; f < 4; ++f) {
            int g = (cp * 4 + f) * 2 + hh;
            LB[nloc * 16 + (g ^ sw7)] = cf[f];
        }
    }
    #pragma unroll
    for (int it = 0; it < 8; ++it) LW[it * 256 + t] = WtD[it * 256 + t];
    __syncthreads();

    // GEMM-B: out = combined @ dec_w  (A = in-LDS combined frags, lane = outcol)
    f32x16 o0 = {}, o1 = {};
    {
        float b0 = dec_b[cp * 64 + l31], b1 = dec_b[cp * 64 + 32 + l31];
        #pragma unroll
        for (int r = 0; r < 16; ++r) { o0[r] = b0; o1[r] = b1; }
    }
    #pragma unroll
    for (int ks = 0; ks < 8; ++ks) {
        int so = ((ks * 2 + hh) ^ sw7) << 4;
        s16x8 af = *(const s16x8*)(lb + nloc * 256 + so);
        s16x8 w0 = *(const s16x8*)(lw + (cp * 64 + l31) * 256 + so);
        s16x8 w1 = *(const s16x8*)(lw + (cp * 64 + 32 + l31) * 256 + so);
        o0 = __builtin_amdgcn_mfma_f32_32x32x16_bf16(af, w0, o0, 0, 0, 0);
        o1 = __builtin_amdgcn_mfma_f32_32x32x16_bf16(af, w1, o1, 0, 0, 0);
    }
    #pragma unroll
    for (int r = 0; r < 16; ++r) {
        int nd = ng * 32 + (r & 3) + 8 * (r >> 2) + 4 * hh;
        if (nd < nrem) {
            float* row = out + (size_t)(node0 + nd) * 128 + cp * 64;
            row[l31]      = o0[r];
            row[32 + l31] = o1[r];
        }
    }
}

// ---------------------------------------------------------------------------
// partA: LDS radix partition of edges by range r = src>>7.  One global atomic
// per (block, range) instead of per edge; packed (src<<16|dst) u32 entries.
// ---------------------------------------------------------------------------
__global__ __launch_bounds__(256) void k_partA(
    const int* __restrict__ src, const int* __restrict__ dst,
    int* __restrict__ gcur, u32* __restrict__ part)
{
    __shared__ int hist[NRANGE];
    __shared__ int base[NRANGE];
    const int t = threadIdx.x;
    const int e0 = blockIdx.x * EPBA;

    for (int i = t; i < NRANGE; i += 256) hist[i] = 0;
    __syncthreads();
    #pragma unroll 4
    for (int k = 0; k < EPBA / 256; ++k) {
        int e = e0 + k * 256 + t;
        if (e < N_EDGES) atomicAdd(&hist[src[e] >> 7], 1);
    }
    __syncthreads();
    for (int i = t; i < NRANGE; i += 256) {
        int h = hist[i];
        base[i] = h ? atomicAdd(&gcur[i], h) : 0;
    }
    __syncthreads();
    for (int i = t; i < NRANGE; i += 256) hist[i] = 0;
    __syncthreads();
    #pragma unroll 4
    for (int k = 0; k < EPBA / 256; ++k) {
        int e = e0 + k * 256 + t;
        if (e < N_EDGES) {
            int s = src[e], d = dst[e];
            int r = s >> 7;
            int p = base[r] + atomicAdd(&hist[r], 1);
            part[(size_t)r * PCAP + p] = ((u32)s << 16) | (u32)d;
        }
    }
}

// ---------------------------------------------------------------------------
// partB: one block per range (128 nodes). Bin the range's contiguous entries
// by exact src in LDS, then fully-coalesced burst write of buckets + counts.
// ---------------------------------------------------------------------------
__global__ __launch_bounds__(256) void k_partB(
    const int* __restrict__ gcur, const u32* __restrict__ part,
    int* __restrict__ counts, u32* __restrict__ bucket)
{
    __shared__ int cnt[128];
    __shared__ u32 lbuck[128 * CAP];   // 32 KB
    const int t = threadIdx.x;
    const int r = blockIdx.x;
    const int node0 = r * 128;

    for (int i = t; i < 128; i += 256) cnt[i] = 0;
    __syncthreads();
    const int total = gcur[r];
    for (int i = t; i < total; i += 256) {
        u32 en = part[(size_t)r * PCAP + i];
        int sl = (en >> 16) & 127;
        int p = atomicAdd(&cnt[sl], 1);
        lbuck[sl * CAP + p] = en & 0xFFFFu;
    }
    __syncthreads();
    for (int i = t; i < 128 * CAP; i += 256) {
        int nd = i >> 6;
        if (node0 + nd < N_NODES)
            bucket[(size_t)node0 * CAP + i] = lbuck[i];
    }
    for (int i = t; i < 128; i += 256)
        if (node0 + i < N_NODES) counts[node0 + i] = cnt[i];
}

// ---------------------------------------------------------------------------
// aggr: wave per node. Lane l computes e_l = exp(sig[node].sig[dst_l]) in
// parallel (cnt <= CAP = 64 lanes); den via shfl_xor reduce; PV loop
// broadcasts (e_k, d_k) via shfl. msg/comm rows pre-swizzled bf16.
// ---------------------------------------------------------------------------
__global__ __launch_bounds__(256) void k_aggr_s(
    const int* __restrict__ counts, const u32* __restrict__ bucket,
    const u32* __restrict__ sig_bf,
    const char* __restrict__ msg_g, char* __restrict__ comm)
{
    const int wave = threadIdx.x >> 6;
    const int lane = threadIdx.x & 63;
    int node = blockIdx.x * 4 + wave;
    if (node >= N_NODES) return;
    const int cnt = counts[node];
    const u32* bk = bucket + (size_t)node * CAP;

    // lane-parallel score phase
    int dl = (lane < cnt) ? (int)bk[lane] : 0;
    const uint4* pn = (const uint4*)(sig_bf + (size_t)node * 8);
    uint4 na = pn[0], nb = pn[1];
    float el = 0.f;
    if (lane < cnt) {
        const uint4* pd = (const uint4*)(sig_bf + (size_t)dl * 8);
        uint4 da = pd[0], db = pd[1];
        float dot = dotpair(na.x, da.x) + dotpair(na.y, da.y)
                  + dotpair(na.z, da.z) + dotpair(na.w, da.w)
                  + dotpair(nb.x, db.x) + dotpair(nb.y, db.y)
                  + dotpair(nb.z, db.z) + dotpair(nb.w, db.w);
        el = __expf(dot);   // |dot|<=1 (unit sigs): segment_max elision exact
    }
    float den = el;
    #pragma unroll
    for (int o = 1; o < 64; o <<= 1) den += __shfl_xor(den, o);

    // PV phase: lane = 2 dims
    const int lo4 = 4 * lane;
    float ax = 0.f, ay = 0.f;
    int k = 0;
    for (; k + 4 <= cnt; k += 4) {
        float e0 = __shfl(el, k),     e1 = __shfl(el, k + 1);
        float e2 = __shfl(el, k + 2), e3 = __shfl(el, k + 3);
        int d0 = __shfl(dl, k),     d1 = __shfl(dl, k + 1);
        int d2 = __shfl(dl, k + 2), d3 = __shfl(dl, k + 3);
        u32 m0 = *(const u32*)(msg_g + (size_t)d0 * 256 + (lo4 ^ ((d0 & 7) << 4)));
        u32 m1 = *(const u32*)(msg_g + (size_t)d1 * 256 + (lo4 ^ ((d1 & 7) << 4)));
        u32 m2 = *(const u32*)(msg_g + (size_t)d2 * 256 + (lo4 ^ ((d2 & 7) << 4)));
        u32 m3 = *(const u32*)(msg_g + (size_t)d3 * 256 + (lo4 ^ ((d3 & 7) << 4)));
        ax += e0 * bf2f(m0 & 0xFFFF) + e1 * bf2f(m1 & 0xFFFF)
            + e2 * bf2f(m2 & 0xFFFF) + e3 * bf2f(m3 & 0xFFFF);
        ay += e0 * bf2f(m0 >> 16) + e1 * bf2f(m1 >> 16)
            + e2 * bf2f(m2 >> 16) + e3 * bf2f(m3 >> 16);
    }
    for (; k < cnt; ++k) {
        float ev = __shfl(el, k);
        int dn = __shfl(dl, k);
        u32 m = *(const u32*)(msg_g + (size_t)dn * 256 + (lo4 ^ ((dn & 7) << 4)));
        ax += ev * bf2f(m & 0xFFFF);
        ay += ev * bf2f(m >> 16);
    }
    float inv = (den > 0.f) ? (1.0f / den) : 0.f;
    *(u32*)(comm + (size_t)node * 256 + (lo4 ^ ((node & 7) << 4))) = pkbf(ax * inv, ay * inv);
}

// ---------------------------------------------------------------------------
extern "C" void kernel_launch(void* const* d_in, const int* in_sizes, int n_in,
                              void* d_out, int out_size, void* d_ws, size_t ws_size,
                              hipStream_t stream)
{
    const float* x     = (const float*)d_in[0];
    const int*   ei    = (const int*)  d_in[1];
    const float* enc_w = (const float*)d_in[2];
    const float* enc_b = (const float*)d_in[3];
    const float* sig_w = (const float*)d_in[4];
    const float* sig_b = (const float*)d_in[5];
    const float* msg_w = (const float*)d_in[6];
    const float* msg_b = (const float*)d_in[7];
    const float* agg_w = (const float*)d_in[8];
    const float* agg_b = (const float*)d_in[9];
    const float* dec_w = (const float*)d_in[10];
    const float* dec_b = (const float*)d_in[11];
    float* out = (float*)d_out;

    const int* src = ei;            // edge_index[0]
    const int* dst = ei + N_EDGES;  // edge_index[1]

    // workspace layout (bytes), ~57 MB
    char* p = (char*)d_ws;
    uint4* h_g   = (uint4*)p;  p += (size_t)N_NODES * 256;  // bf16 rows, swizzled
    uint4* msg_g = (uint4*)p;  p += (size_t)N_NODES * 256;
    uint4* comm  = (uint4*)p;  p += (size_t)N_NODES * 256;
    u32*   sig_bf = (u32*)p;   p += (size_t)N_NODES * 32;   // bf16 sig rows
    u32*   bucket = (u32*)p;   p += (size_t)N_NODES * CAP * 4;
    int*   counts = (int*)p;   p += (size_t)N_NODES * 4;
    u32*   part   = (u32*)p;   p += (size_t)NRANGE * PCAP * 4;
    int*   gcur   = (int*)p;   p += 2048;
    uint4* WtE  = (uint4*)p; p += 32768;
    uint4* WtM  = (uint4*)p; p += 32768;
    uint4* WtD  = (uint4*)p; p += 32768;
    uint4* WtA0 = (uint4*)p; p += 32768;
    uint4* WtA1 = (uint4*)p; p += 32768;
    uint4* WtS  = (uint4*)p; p += 8192;

    hipMemsetAsync(gcur, 0, NRANGE * sizeof(int), stream);

    k_prep<<<42, 256, 0, stream>>>(enc_w, msg_w, sig_w, agg_w, dec_w,
                                   WtE, WtM, WtD, WtA0, WtA1, WtS);
    k_encode_m<<<(N_NODES + 127) / 128, 256, 0, stream>>>(
        x, WtE, WtM, WtS, enc_b, sig_b, msg_b, h_g, sig_bf, msg_g);
    k_partA<<<NBA, 256, 0, stream>>>(src, dst, gcur, part);
    k_partB<<<NRANGE, 256, 0, stream>>>(gcur, part, counts, bucket);
    k_aggr_s<<<(N_NODES + 3) / 4, 256, 0, stream>>>(
        counts, bucket, sig_bf, (const char*)msg_g, (char*)comm);
    k_decode_m<<<(N_NODES + 63) / 64, 256, 0, stream>>>(
        h_g, comm, WtA0, WtA1, WtD, agg_b, dec_b, out);
}

// Round 13
// 118.273 us; speedup vs baseline: 1.2199x; 1.0182x over previous
//
#include <hip/hip_runtime.h>
#include <math.h>

#define N_NODES 50000
#define N_EDGES 800000
#define CAP 64     // bucket capacity per node (max degree <= 64, validated r7-r12)
#define NRANGE 782 // ceil(N_NODES/64) ranges of 64 nodes
#define PCAP 1280  // part capacity per range (mean 1023, +8 sigma)
#define EPBA 8192  // edges per partA block
#define NBA 98     // ceil(N_EDGES/EPBA)

typedef __attribute__((ext_vector_type(8)))  short s16x8;   // 8 bf16 (4 VGPR)
typedef __attribute__((ext_vector_type(16))) float f32x16;  // MFMA acc
typedef unsigned int u32;
typedef unsigned short u16;

union U16B { uint4 u; s16x8 s; };

// f32 -> bf16 bits, round-to-nearest-even
__device__ __forceinline__ u32 bfr(float f) {
    u32 u = __float_as_uint(f);
    return (u + 0x7FFFu + ((u >> 16) & 1u)) >> 16;
}
__device__ __forceinline__ u32 pkbf(float a, float b) { return bfr(a) | (bfr(b) << 16); }
__device__ __forceinline__ float bf2f(u32 b) { return __uint_as_float(b << 16); }
// dot of a bf16x2 pair against another
__device__ __forceinline__ float dotpair(u32 a, u32 b) {
    return bf2f(a & 0xFFFFu) * bf2f(b & 0xFFFFu) + bf2f(a >> 16) * bf2f(b >> 16);
}

// Build an MFMA input frag (lane-dim = D-col, k = 8*(lane>>5)+e) from 8 f32
// D-regs of a 32x32x16 accumulator (rows (r&3)+8*(r>>2)+4*hh), via bf16 pack
// + half-wave exchange. d8 must be compile-time indexed by caller.
__device__ __forceinline__ uint4 buildfrag(const float* d8, int hh) {
    u32 P = pkbf(d8[0], d8[1]), Q = pkbf(d8[2], d8[3]);
    u32 R = pkbf(d8[4], d8[5]), S = pkbf(d8[6], d8[7]);
    u32 sP = (u32)__shfl_xor((int)P, 32);
    u32 sQ = (u32)__shfl_xor((int)Q, 32);
    u32 sR = (u32)__shfl_xor((int)R, 32);
    u32 sS = (u32)__shfl_xor((int)S, 32);
    uint4 f;
    f.x = hh ? sR : P;  f.y = hh ? sS : Q;
    f.z = hh ? R : sP;  f.w = hh ? S : sQ;
    return f;
}
#define BUILDF(OUT, ACC, Q, HH) do { \
    float _td[8]; \
    _Pragma("unroll") for (int _z = 0; _z < 8; ++_z) _td[_z] = (ACC)[(Q)*8 + _z]; \
    (OUT) = buildfrag(_td, HH); } while (0)
#define BUILDR(OUT, ACC, Q, HH) do { \
    float _td[8]; \
    _Pragma("unroll") for (int _z = 0; _z < 8; ++_z) _td[_z] = fmaxf((ACC)[(Q)*8 + _z], 0.f); \
    (OUT) = buildfrag(_td, HH); } while (0)

// ---------------------------------------------------------------------------
// prep: weights -> bf16, transposed [col][k] rows (256B), granule-XOR swizzled
// ---------------------------------------------------------------------------
__global__ __launch_bounds__(256) void k_prep(
    const float* __restrict__ enc_w, const float* __restrict__ msg_w,
    const float* __restrict__ sig_w, const float* __restrict__ agg_w,
    const float* __restrict__ dec_w,
    uint4* __restrict__ WtE, uint4* __restrict__ WtM, uint4* __restrict__ WtD,
    uint4* __restrict__ WtA0, uint4* __restrict__ WtA1, uint4* __restrict__ WtS)
{
    int gid = blockIdx.x * 256 + threadIdx.x;
    if (gid < 10240) {
        int m = gid >> 11, r = gid & 2047;
        int col = r >> 4, s = r & 15;
        const float* W; uint4* D; int kb = 0;
        if      (m == 0) { W = enc_w; D = WtE; }
        else if (m == 1) { W = msg_w; D = WtM; }
        else if (m == 2) { W = dec_w; D = WtD; }
        else if (m == 3) { W = agg_w; D = WtA0; }
        else             { W = agg_w; D = WtA1; kb = 128; }
        float v[8];
        #pragma unroll
        for (int j = 0; j < 8; ++j) v[j] = W[(size_t)(kb + s * 8 + j) * 128 + col];
        uint4 w;
        w.x = pkbf(v[0], v[1]); w.y = pkbf(v[2], v[3]);
        w.z = pkbf(v[4], v[5]); w.w = pkbf(v[6], v[7]);
        D[col * 16 + (s ^ (col & 7))] = w;
    } else if (gid < 10752) {
        int r = gid - 10240;
        int row = r >> 4, s = r & 15;
        float v[8];
        #pragma unroll
        for (int j = 0; j < 8; ++j)
            v[j] = (row < 16) ? sig_w[(size_t)(s * 8 + j) * 16 + row] : 0.0f;
        uint4 w;
        w.x = pkbf(v[0], v[1]); w.y = pkbf(v[2], v[3]);
        w.z = pkbf(v[4], v[5]); w.w = pkbf(v[6], v[7]);
        WtS[row * 16 + (s ^ (row & 7))] = w;
    }
}

// ---------------------------------------------------------------------------
// encode (MFMA): h = x@enc_w+b ; msg = relu(h@msg_w+b) ; sig = l2n(h@sig_w+b)
// Block = 128 nodes, 4 waves x 32 nodes. All GEMMs computed transposed
// (D = W^T x^T) so lane-dim = node; h^T fragments stay in registers.
// h rows pre-swizzled (decode staging); msg rows LINEAR (aggr-only consumer).
// ---------------------------------------------------------------------------
__global__ __launch_bounds__(256) void k_encode_m(
    const float* __restrict__ x,
    const uint4* __restrict__ WtE, const uint4* __restrict__ WtM,
    const uint4* __restrict__ WtS,
    const float* __restrict__ enc_b, const float* __restrict__ sig_b,
    const float* __restrict__ msg_b,
    uint4* __restrict__ h_g, u32* __restrict__ sig_bf, uint4* __restrict__ msg_g)
{
    __shared__ uint4 LB[2048];   // x tile bf16 [128 nodes][16 granules]
    __shared__ uint4 LW[2048];   // weight tile [128 cols][16 granules]
    __shared__ float LS[2176];   // sigWt (8KB) then sig funnel (8.7KB)

    const int t = threadIdx.x;
    const int node0 = blockIdx.x * 128;
    int nrem = N_NODES - node0; if (nrem > 128) nrem = 128;
    const int lane = t & 63, wid = t >> 6;
    const int l31 = lane & 31, hh = lane >> 5;
    const int nloc = wid * 32 + l31;
    const int sw7 = l31 & 7;

    // stage x (f32->bf16, swizzled) + enc weights
    #pragma unroll
    for (int it = 0; it < 8; ++it) {
        int idx = it * 256 + t;
        int nd = idx >> 4, s = idx & 15;
        float4 v0 = make_float4(0, 0, 0, 0), v1 = v0;
        if (nd < nrem) {
            const float4* px = (const float4*)(x + (size_t)(node0 + nd) * 128 + s * 8);
            v0 = px[0]; v1 = px[1];
        }
        uint4 w;
        w.x = pkbf(v0.x, v0.y); w.y = pkbf(v0.z, v0.w);
        w.z = pkbf(v1.x, v1.y); w.w = pkbf(v1.z, v1.w);
        LB[nd * 16 + (s ^ (nd & 7))] = w;
        LW[idx] = WtE[idx];
    }
    __syncthreads();

    const char* lb = (const char*)LB;
    const char* lw = (const char*)LW;

    // GEMM1: h^T = encW^T x^T  (D rows = h-cols, cols = nodes)
    f32x16 a0 = {}, a1 = {}, a2 = {}, a3 = {};
    #pragma unroll
    for (int r = 0; r < 16; ++r) {
        int rr = (r & 3) + 8 * (r >> 2) + 4 * hh;
        a0[r] = enc_b[rr];      a1[r] = enc_b[32 + rr];
        a2[r] = enc_b[64 + rr]; a3[r] = enc_b[96 + rr];
    }
    #pragma unroll
    for (int ks = 0; ks < 8; ++ks) {
        int so = ((ks * 2 + hh) ^ sw7) << 4;
        s16x8 bf = *(const s16x8*)(lb + nloc * 256 + so);
        s16x8 w0 = *(const s16x8*)(lw + l31 * 256 + so);
        s16x8 w1 = *(const s16x8*)(lw + 8192 + l31 * 256 + so);
        s16x8 w2 = *(const s16x8*)(lw + 16384 + l31 * 256 + so);
        s16x8 w3 = *(const s16x8*)(lw + 24576 + l31 * 256 + so);
        a0 = __builtin_amdgcn_mfma_f32_32x32x16_bf16(w0, bf, a0, 0, 0, 0);
        a1 = __builtin_amdgcn_mfma_f32_32x32x16_bf16(w1, bf, a1, 0, 0, 0);
        a2 = __builtin_amdgcn_mfma_f32_32x32x16_bf16(w2, bf, a2, 0, 0, 0);
        a3 = __builtin_amdgcn_mfma_f32_32x32x16_bf16(w3, bf, a3, 0, 0, 0);
    }

    // h^T -> in-register bf16 fragments (k = h-col)
    uint4 hf[8];
    BUILDF(hf[0], a0, 0, hh); BUILDF(hf[1], a0, 1, hh);
    BUILDF(hf[2], a1, 0, hh); BUILDF(hf[3], a1, 1, hh);
    BUILDF(hf[4], a2, 0, hh); BUILDF(hf[5], a2, 1, hh);
    BUILDF(hf[6], a3, 0, hh); BUILDF(hf[7], a3, 1, hh);

    // h rows -> global (pre-swizzled bf16 rows)
    if (nloc < nrem) {
        const size_t rb = (size_t)(node0 + nloc) * 16;
        #pragma unroll
        for (int f = 0; f < 8; ++f) {
            int g = 2 * f + hh;
            h_g[rb + (g ^ sw7)] = hf[f];
        }
    }

    __syncthreads();   // done reading WtE
    #pragma unroll
    for (int it = 0; it < 8; ++it) LW[it * 256 + t] = WtM[it * 256 + t];
    {   // sigWt (8KB) into LS
        uint4* LSu = (uint4*)LS;
        LSu[t] = WtS[t]; LSu[256 + t] = WtS[256 + t];
    }
    __syncthreads();

    // GEMM2: msg^T = msgW^T h^T  (B-operand = in-reg h frags)
    f32x16 m0 = {}, m1 = {}, m2 = {}, m3 = {};
    #pragma unroll
    for (int r = 0; r < 16; ++r) {
        int rr = (r & 3) + 8 * (r >> 2) + 4 * hh;
        m0[r] = msg_b[rr];      m1[r] = msg_b[32 + rr];
        m2[r] = msg_b[64 + rr]; m3[r] = msg_b[96 + rr];
    }
    #pragma unroll
    for (int ks = 0; ks < 8; ++ks) {
        int so = ((ks * 2 + hh) ^ sw7) << 4;
        U16B hb; hb.u = hf[ks];
        s16x8 w0 = *(const s16x8*)(lw + l31 * 256 + so);
        s16x8 w1 = *(const s16x8*)(lw + 8192 + l31 * 256 + so);
        s16x8 w2 = *(const s16x8*)(lw + 16384 + l31 * 256 + so);
        s16x8 w3 = *(const s16x8*)(lw + 24576 + l31 * 256 + so);
        m0 = __builtin_amdgcn_mfma_f32_32x32x16_bf16(w0, hb.s, m0, 0, 0, 0);
        m1 = __builtin_amdgcn_mfma_f32_32x32x16_bf16(w1, hb.s, m1, 0, 0, 0);
        m2 = __builtin_amdgcn_mfma_f32_32x32x16_bf16(w2, hb.s, m2, 0, 0, 0);
        m3 = __builtin_amdgcn_mfma_f32_32x32x16_bf16(w3, hb.s, m3, 0, 0, 0);
    }
    {   // relu + store msg rows (LINEAR layout)
        uint4 mf[8];
        BUILDR(mf[0], m0, 0, hh); BUILDR(mf[1], m0, 1, hh);
        BUILDR(mf[2], m1, 0, hh); BUILDR(mf[3], m1, 1, hh);
        BUILDR(mf[4], m2, 0, hh); BUILDR(mf[5], m2, 1, hh);
        BUILDR(mf[6], m3, 0, hh); BUILDR(mf[7], m3, 1, hh);
        if (nloc < nrem) {
            const size_t rb = (size_t)(node0 + nloc) * 16;
            #pragma unroll
            for (int f = 0; f < 8; ++f) {
                int g = 2 * f + hh;
                msg_g[rb + g] = mf[f];
            }
        }
    }

    // GEMM3: sig^T = sigW^T h^T  (rows 16..31 of sigWt are zero)
    f32x16 sg = {};
    #pragma unroll
    for (int r = 0; r < 8; ++r) {
        int rr = (r & 3) + 8 * (r >> 2) + 4 * hh;   // < 16
        sg[r] = sig_b[rr];
    }
    const char* lsw = (const char*)LS;
    #pragma unroll
    for (int ks = 0; ks < 8; ++ks) {
        int so = ((ks * 2 + hh) ^ sw7) << 4;
        s16x8 aw = *(const s16x8*)(lsw + l31 * 256 + so);
        U16B hb; hb.u = hf[ks];
        sg = __builtin_amdgcn_mfma_f32_32x32x16_bf16(aw, hb.s, sg, 0, 0, 0);
    }
    float ss = 0.f;
    #pragma unroll
    for (int r = 0; r < 8; ++r) ss += sg[r] * sg[r];
    ss += __shfl_xor(ss, 32);
    float inv = 1.0f / fmaxf(sqrtf(ss), 1e-12f);
    __syncthreads();   // all sigWt reads done before funnel overwrite
    #pragma unroll
    for (int r = 0; r < 8; ++r) {
        int sc = (r & 3) + 8 * (r >> 2) + 4 * hh;
        LS[nloc * 17 + sc] = sg[r] * inv;
    }
    __syncthreads();
    // sig rows -> global as bf16 pairs (8 u32 per node)
    #pragma unroll
    for (int it = 0; it < 4; ++it) {
        int idx = it * 256 + t;           // 1024 = 128 nodes x 8 u32
        int nd = idx >> 3, c2 = idx & 7;
        if (nd < nrem)
            sig_bf[(size_t)(node0 + nd) * 8 + c2] =
                pkbf(LS[nd * 17 + 2 * c2], LS[nd * 17 + 2 * c2 + 1]);
    }
}

// ---------------------------------------------------------------------------
// decode (MFMA): out = relu([h|comm]@agg_w+b) @ dec_w + b
// Block = 64 nodes, 4 waves: wave = (node half) x (64 col half).
// ---------------------------------------------------------------------------
__global__ __launch_bounds__(256) void k_decode_m(
    const uint4* __restrict__ h_g, const uint4* __restrict__ comm,
    const uint4* __restrict__ WtA0, const uint4* __restrict__ WtA1,
    const uint4* __restrict__ WtD,
    const float* __restrict__ agg_b, const float* __restrict__ dec_b,
    float* __restrict__ out)
{
    __shared__ uint4 LB[2048];   // Bcat [64][32 granules]; later Lcomb [64][16]
    __shared__ uint4 LW[2048];

    const int t = threadIdx.x;
    const int node0 = blockIdx.x * 64;
    int nrem = N_NODES - node0; if (nrem > 64) nrem = 64;
    const int lane = t & 63, wid = t >> 6;
    const int l31 = lane & 31, hh = lane >> 5;
    const int ng = wid & 1, cp = wid >> 1;
    const int nloc = ng * 32 + l31;
    const int sw7 = l31 & 7;

    // stage Bcat = [h | comm] bf16 (both pre-swizzled: linear copy)
    #pragma unroll
    for (int it = 0; it < 8; ++it) {
        int idx = it * 256 + t;
        int nd = idx >> 5, g = idx & 31;
        uint4 v = make_uint4(0, 0, 0, 0);
        if (nd < nrem)
            v = (g < 16) ? h_g[(size_t)(node0 + nd) * 16 + g]
                         : comm[(size_t)(node0 + nd) * 16 + (g - 16)];
        LB[nd * 32 + g] = v;
        LW[idx] = WtA0[idx];
    }
    __syncthreads();

    const char* lb = (const char*)LB;
    const char* lw = (const char*)LW;

    // GEMM-A: combined^T = aggW^T [h|comm]^T  (K = 256, staged in halves)
    f32x16 c0 = {}, c1 = {};
    #pragma unroll
    for (int r = 0; r < 16; ++r) {
        int rr = (r & 3) + 8 * (r >> 2) + 4 * hh;
        c0[r] = agg_b[cp * 64 + rr];
        c1[r] = agg_b[cp * 64 + 32 + rr];
    }
    #pragma unroll
    for (int ks = 0; ks < 8; ++ks) {
        int so = ((ks * 2 + hh) ^ sw7) << 4;
        s16x8 bf = *(const s16x8*)(lb + nloc * 512 + so);
        s16x8 w0 = *(const s16x8*)(lw + (cp * 64 + l31) * 256 + so);
        s16x8 w1 = *(const s16x8*)(lw + (cp * 64 + 32 + l31) * 256 + so);
        c0 = __builtin_amdgcn_mfma_f32_32x32x16_bf16(w0, bf, c0, 0, 0, 0);
        c1 = __builtin_amdgcn_mfma_f32_32x32x16_bf16(w1, bf, c1, 0, 0, 0);
    }
    __syncthreads();
    #pragma unroll
    for (int it = 0; it < 8; ++it) LW[it * 256 + t] = WtA1[it * 256 + t];
    __syncthreads();
    #pragma unroll
    for (int ks = 8; ks < 16; ++ks) {
        int so = ((ks * 2 + hh) ^ sw7) << 4;            // bit4 kept: comm half
        int so2 = (((ks - 8) * 2 + hh) ^ sw7) << 4;
        s16x8 bf = *(const s16x8*)(lb + nloc * 512 + so);
        s16x8 w0 = *(const s16x8*)(lw + (cp * 64 + l31) * 256 + so2);
        s16x8 w1 = *(const s16x8*)(lw + (cp * 64 + 32 + l31) * 256 + so2);
        c0 = __builtin_amdgcn_mfma_f32_32x32x16_bf16(w0, bf, c0, 0, 0, 0);
        c1 = __builtin_amdgcn_mfma_f32_32x32x16_bf16(w1, bf, c1, 0, 0, 0);
    }
    __syncthreads();   // all Bcat / WtA1 reads done

    // relu + build combined fragments; exchange across waves via LB (Lcomb)
    {
        uint4 cf[4];
        BUILDR(cf[0], c0, 0, hh); BUILDR(cf[1], c0, 1, hh);
        BUILDR(cf[2], c1, 0, hh); BUILDR(cf[3], c1, 1, hh);
        #pragma unroll
        for (int f = 0; f < 4; ++f) {
            int g = (cp * 4 + f) * 2 + hh;
            LB[nloc * 16 + (g ^ sw7)] = cf[f];
        }
    }
    #pragma unroll
    for (int it = 0; it < 8; ++it) LW[it * 256 + t] = WtD[it * 256 + t];
    __syncthreads();

    // GEMM-B: out = combined @ dec_w  (A = in-LDS combined frags, lane = outcol)
    f32x16 o0 = {}, o1 = {};
    {
        float b0 = dec_b[cp * 64 + l31], b1 = dec_b[cp * 64 + 32 + l31];
        #pragma unroll
        for (int r = 0; r < 16; ++r) { o0[r] = b0; o1[r] = b1; }
    }
    #pragma unroll
    for (int ks = 0; ks < 8; ++ks) {
        int so = ((ks * 2 + hh) ^ sw7) << 4;
        s16x8 af = *(const s16x8*)(lb + nloc * 256 + so);
        s16x8 w0 = *(const s16x8*)(lw + (cp * 64 + l31) * 256 + so);
        s16x8 w1 = *(const s16x8*)(lw + (cp * 64 + 32 + l31) * 256 + so);
        o0 = __builtin_amdgcn_mfma_f32_32x32x16_bf16(af, w0, o0, 0, 0, 0);
        o1 = __builtin_amdgcn_mfma_f32_32x32x16_bf16(af, w1, o1, 0, 0, 0);
    }
    #pragma unroll
    for (int r = 0; r < 16; ++r) {
        int nd = ng * 32 + (r & 3) + 8 * (r >> 2) + 4 * hh;
        if (nd < nrem) {
            float* row = out + (size_t)(node0 + nd) * 128 + cp * 64;
            row[l31]      = o0[r];
            row[32 + l31] = o1[r];
        }
    }
}

// ---------------------------------------------------------------------------
// partA: LDS radix partition of edges by range r = src>>6.  One global atomic
// per (block, range) instead of per edge; packed (src<<16|dst) u32 entries.
// ---------------------------------------------------------------------------
__global__ __launch_bounds__(256) void k_partA(
    const int* __restrict__ src, const int* __restrict__ dst,
    int* __restrict__ gcur, u32* __restrict__ part)
{
    __shared__ int hist[NRANGE];
    __shared__ int base[NRANGE];
    const int t = threadIdx.x;
    const int e0 = blockIdx.x * EPBA;

    for (int i = t; i < NRANGE; i += 256) hist[i] = 0;
    __syncthreads();
    #pragma unroll 4
    for (int k = 0; k < EPBA / 256; ++k) {
        int e = e0 + k * 256 + t;
        if (e < N_EDGES) atomicAdd(&hist[src[e] >> 6], 1);
    }
    __syncthreads();
    for (int i = t; i < NRANGE; i += 256) {
        int h = hist[i];
        base[i] = h ? atomicAdd(&gcur[i], h) : 0;
    }
    __syncthreads();
    for (int i = t; i < NRANGE; i += 256) hist[i] = 0;
    __syncthreads();
    #pragma unroll 4
    for (int k = 0; k < EPBA / 256; ++k) {
        int e = e0 + k * 256 + t;
        if (e < N_EDGES) {
            int s = src[e], d = dst[e];
            int r = s >> 6;
            int p = base[r] + atomicAdd(&hist[r], 1);
            part[(size_t)r * PCAP + p] = ((u32)s << 16) | (u32)d;
        }
    }
}

// ---------------------------------------------------------------------------
// fused partB + aggr: one block per 64-node range.
//  phase 1: bin entries into LDS (d, e=exp(sig.sig)) pairs; den via ds_add_f32
//  phase 2: PV — 2 nodes per wave (half-wave each, lane = 4 dims, 8B loads);
//           (d,e) via one ds_read_b64 broadcast per edge. comm rows swizzled.
// ---------------------------------------------------------------------------
__global__ __launch_bounds__(256) void k_pb_aggr(
    const int* __restrict__ gcur, const u32* __restrict__ part,
    const u32* __restrict__ sig_bf,
    const char* __restrict__ msg_g, char* __restrict__ comm)
{
    __shared__ int   cnt[64];
    __shared__ float lden[64];
    __shared__ int2  lde[64 * CAP];   // 32 KB (d, e) pairs

    const int t = threadIdx.x;
    const int r = blockIdx.x;
    const int node0 = r * 64;

    if (t < 64) { cnt[t] = 0; lden[t] = 0.f; }
    __syncthreads();

    const int total = gcur[r];
    for (int i = t; i < total; i += 256) {
        u32 en = part[(size_t)r * PCAP + i];
        int s = (int)(en >> 16), d = (int)(en & 0xFFFFu);
        const uint4* ps = (const uint4*)(sig_bf + (size_t)s * 8);
        const uint4* pd = (const uint4*)(sig_bf + (size_t)d * 8);
        uint4 sa = ps[0], sb = ps[1];
        uint4 da = pd[0], db = pd[1];
        float dot = dotpair(sa.x, da.x) + dotpair(sa.y, da.y)
                  + dotpair(sa.z, da.z) + dotpair(sa.w, da.w)
                  + dotpair(sb.x, db.x) + dotpair(sb.y, db.y)
                  + dotpair(sb.z, db.z) + dotpair(sb.w, db.w);
        float e = __expf(dot);   // |dot|<=1 (unit sigs): segment_max elision exact
        int sl = s & 63;
        int p = atomicAdd(&cnt[sl], 1);
        lde[sl * CAP + p] = make_int2(d, __float_as_int(e));
        atomicAdd(&lden[sl], e);
    }
    __syncthreads();

    // PV: wave wid covers nodes [wid*16, wid*16+16), 2 at a time (half-waves)
    const int lane = t & 63, wid = t >> 6;
    const int l31 = lane & 31, hh = lane >> 5;
    #pragma unroll
    for (int g = 0; g < 8; ++g) {
        const int nloc = wid * 16 + 2 * g + hh;
        const int node = node0 + nloc;
        const int cn = cnt[nloc];
        float a0 = 0.f, a1 = 0.f, a2 = 0.f, a3 = 0.f;
        for (int k = 0; k < cn; ++k) {
            int2 de = lde[nloc * CAP + k];
            float e = __int_as_float(de.y);
            uint2 m = *(const uint2*)(msg_g + (size_t)de.x * 256 + 8 * l31);
            a0 += e * bf2f(m.x & 0xFFFFu);
            a1 += e * bf2f(m.x >> 16);
            a2 += e * bf2f(m.y & 0xFFFFu);
            a3 += e * bf2f(m.y >> 16);
        }
        float den = lden[nloc];
        float inv = (den > 0.f) ? (1.0f / den) : 0.f;
        if (node < N_NODES) {
            uint2 w;
            w.x = pkbf(a0 * inv, a1 * inv);
            w.y = pkbf(a2 * inv, a3 * inv);
            *(uint2*)(comm + (size_t)node * 256 + ((8 * l31) ^ ((node & 7) << 4))) = w;
        }
    }
}

// ---------------------------------------------------------------------------
extern "C" void kernel_launch(void* const* d_in, const int* in_sizes, int n_in,
                              void* d_out, int out_size, void* d_ws, size_t ws_size,
                              hipStream_t stream)
{
    const float* x     = (const float*)d_in[0];
    const int*   ei    = (const int*)  d_in[1];
    const float* enc_w = (const float*)d_in[2];
    const float* enc_b = (const float*)d_in[3];
    const float* sig_w = (const float*)d_in[4];
    const float* sig_b = (const float*)d_in[5];
    const float* msg_w = (const float*)d_in[6];
    const float* msg_b = (const float*)d_in[7];
    const float* agg_w = (const float*)d_in[8];
    const float* agg_b = (const float*)d_in[9];
    const float* dec_w = (const float*)d_in[10];
    const float* dec_b = (const float*)d_in[11];
    float* out = (float*)d_out;

    const int* src = ei;            // edge_index[0]
    const int* dst = ei + N_EDGES;  // edge_index[1]

    // workspace layout (bytes), ~45 MB
    char* p = (char*)d_ws;
    uint4* h_g   = (uint4*)p;  p += (size_t)N_NODES * 256;  // bf16 rows, swizzled
    uint4* msg_g = (uint4*)p;  p += (size_t)N_NODES * 256;  // bf16 rows, LINEAR
    uint4* comm  = (uint4*)p;  p += (size_t)N_NODES * 256;  // bf16 rows, swizzled
    u32*   sig_bf = (u32*)p;   p += (size_t)N_NODES * 32;   // bf16 sig rows
    u32*   part   = (u32*)p;   p += (size_t)NRANGE * PCAP * 4;
    int*   gcur   = (int*)p;   p += 4096;
    uint4* WtE  = (uint4*)p; p += 32768;
    uint4* WtM  = (uint4*)p; p += 32768;
    uint4* WtD  = (uint4*)p; p += 32768;
    uint4* WtA0 = (uint4*)p; p += 32768;
    uint4* WtA1 = (uint4*)p; p += 32768;
    uint4* WtS  = (uint4*)p; p += 8192;

    hipMemsetAsync(gcur, 0, NRANGE * sizeof(int), stream);

    k_prep<<<42, 256, 0, stream>>>(enc_w, msg_w, sig_w, agg_w, dec_w,
                                   WtE, WtM, WtD, WtA0, WtA1, WtS);
    k_encode_m<<<(N_NODES + 127) / 128, 256, 0, stream>>>(
        x, WtE, WtM, WtS, enc_b, sig_b, msg_b, h_g, sig_bf, msg_g);
    k_partA<<<NBA, 256, 0, stream>>>(src, dst, gcur, part);
    k_pb_aggr<<<NRANGE, 256, 0, stream>>>(
        gcur, part, sig_bf, (const char*)msg_g, (char*)comm);
    k_decode_m<<<(N_NODES + 63) / 64, 256, 0, stream>>>(
        h_g, comm, WtA0, WtA1, WtD, agg_b, dec_b, out);
}

// Round 14
// 101.755 us; speedup vs baseline: 1.4179x; 1.1623x over previous
//
#include <hip/hip_runtime.h>
#include <math.h>

#define N_NODES 50000
#define N_EDGES 800000
#define CAP 64     // bucket capacity per node (max degree <= 64, validated r7-r13)
#define NRANGE 782 // ceil(N_NODES/64) ranges of 64 nodes
#define PCAP 1280  // part capacity per range (mean 1023, +8 sigma)
#define EPBA 8192  // edges per partA block
#define NBA 98     // ceil(N_EDGES/EPBA)
#define NBE 391    // encode blocks: ceil(50000/128)
#define NCHUNK 4   // dst chunks of 12500 nodes (3.2 MB msg each, fits XCD L2)

typedef __attribute__((ext_vector_type(8)))  short s16x8;   // 8 bf16 (4 VGPR)
typedef __attribute__((ext_vector_type(16))) float f32x16;  // MFMA acc
typedef unsigned int u32;
typedef unsigned short u16;

union U16B { uint4 u; s16x8 s; };

// f32 -> bf16 bits, round-to-nearest-even
__device__ __forceinline__ u32 bfr(float f) {
    u32 u = __float_as_uint(f);
    return (u + 0x7FFFu + ((u >> 16) & 1u)) >> 16;
}
__device__ __forceinline__ u32 pkbf(float a, float b) { return bfr(a) | (bfr(b) << 16); }
__device__ __forceinline__ float bf2f(u32 b) { return __uint_as_float(b << 16); }
// dot of a bf16x2 pair against another
__device__ __forceinline__ float dotpair(u32 a, u32 b) {
    return bf2f(a & 0xFFFFu) * bf2f(b & 0xFFFFu) + bf2f(a >> 16) * bf2f(b >> 16);
}

// Build an MFMA input frag (lane-dim = D-col, k = 8*(lane>>5)+e) from 8 f32
// D-regs of a 32x32x16 accumulator (rows (r&3)+8*(r>>2)+4*hh), via bf16 pack
// + half-wave exchange. d8 must be compile-time indexed by caller.
__device__ __forceinline__ uint4 buildfrag(const float* d8, int hh) {
    u32 P = pkbf(d8[0], d8[1]), Q = pkbf(d8[2], d8[3]);
    u32 R = pkbf(d8[4], d8[5]), S = pkbf(d8[6], d8[7]);
    u32 sP = (u32)__shfl_xor((int)P, 32);
    u32 sQ = (u32)__shfl_xor((int)Q, 32);
    u32 sR = (u32)__shfl_xor((int)R, 32);
    u32 sS = (u32)__shfl_xor((int)S, 32);
    uint4 f;
    f.x = hh ? sR : P;  f.y = hh ? sS : Q;
    f.z = hh ? R : sP;  f.w = hh ? S : sQ;
    return f;
}
#define BUILDF(OUT, ACC, Q, HH) do { \
    float _td[8]; \
    _Pragma("unroll") for (int _z = 0; _z < 8; ++_z) _td[_z] = (ACC)[(Q)*8 + _z]; \
    (OUT) = buildfrag(_td, HH); } while (0)
#define BUILDR(OUT, ACC, Q, HH) do { \
    float _td[8]; \
    _Pragma("unroll") for (int _z = 0; _z < 8; ++_z) _td[_z] = fmaxf((ACC)[(Q)*8 + _z], 0.f); \
    (OUT) = buildfrag(_td, HH); } while (0)

// ---------------------------------------------------------------------------
// prep: weights -> bf16, transposed [col][k] rows (256B), granule-XOR swizzled
// Also zeroes gcur (saves the memset dispatch).
// ---------------------------------------------------------------------------
__global__ __launch_bounds__(256) void k_prep(
    const float* __restrict__ enc_w, const float* __restrict__ msg_w,
    const float* __restrict__ sig_w, const float* __restrict__ agg_w,
    const float* __restrict__ dec_w,
    uint4* __restrict__ WtE, uint4* __restrict__ WtM, uint4* __restrict__ WtD,
    uint4* __restrict__ WtA0, uint4* __restrict__ WtA1, uint4* __restrict__ WtS,
    int* __restrict__ gcur)
{
    int gid = blockIdx.x * 256 + threadIdx.x;
    if (gid < NRANGE) gcur[gid] = 0;
    if (gid < 10240) {
        int m = gid >> 11, r = gid & 2047;
        int col = r >> 4, s = r & 15;
        const float* W; uint4* D; int kb = 0;
        if      (m == 0) { W = enc_w; D = WtE; }
        else if (m == 1) { W = msg_w; D = WtM; }
        else if (m == 2) { W = dec_w; D = WtD; }
        else if (m == 3) { W = agg_w; D = WtA0; }
        else             { W = agg_w; D = WtA1; kb = 128; }
        float v[8];
        #pragma unroll
        for (int j = 0; j < 8; ++j) v[j] = W[(size_t)(kb + s * 8 + j) * 128 + col];
        uint4 w;
        w.x = pkbf(v[0], v[1]); w.y = pkbf(v[2], v[3]);
        w.z = pkbf(v[4], v[5]); w.w = pkbf(v[6], v[7]);
        D[col * 16 + (s ^ (col & 7))] = w;
    } else if (gid < 10752) {
        int r = gid - 10240;
        int row = r >> 4, s = r & 15;
        float v[8];
        #pragma unroll
        for (int j = 0; j < 8; ++j)
            v[j] = (row < 16) ? sig_w[(size_t)(s * 8 + j) * 16 + row] : 0.0f;
        uint4 w;
        w.x = pkbf(v[0], v[1]); w.y = pkbf(v[2], v[3]);
        w.z = pkbf(v[4], v[5]); w.w = pkbf(v[6], v[7]);
        WtS[row * 16 + (s ^ (row & 7))] = w;
    }
}

// ---------------------------------------------------------------------------
// fused encode + partA (grid-level task fusion; partA is a pure index shuffle
// with no dependence on encode outputs):
//   blockIdx <  NBE : MFMA encode (h, msg, sig)
//   blockIdx >= NBE : LDS radix partition of edges by range r = src>>6
// 489 blocks total, all co-resident at 2 blocks/CU (74KB LDS envelope).
// ---------------------------------------------------------------------------
__global__ __launch_bounds__(256) void k_enc_part(
    const float* __restrict__ x,
    const uint4* __restrict__ WtE, const uint4* __restrict__ WtM,
    const uint4* __restrict__ WtS,
    const float* __restrict__ enc_b, const float* __restrict__ sig_b,
    const float* __restrict__ msg_b,
    uint4* __restrict__ h_g, u32* __restrict__ sig_bf, uint4* __restrict__ msg_g,
    const int* __restrict__ src, const int* __restrict__ dst,
    int* __restrict__ gcur, u32* __restrict__ part)
{
    __shared__ uint4 LB[2048];   // x tile bf16 / partA hist+base
    __shared__ uint4 LW[2048];   // weight tile [128 cols][16 granules]
    __shared__ float LS[2176];   // sigWt (8KB) then sig funnel (8.7KB)

    const int t = threadIdx.x;

    if (blockIdx.x >= NBE) {
        // ---------------- partA path ----------------
        int* hist = (int*)LB;
        int* base = hist + NRANGE;
        const int e0 = (blockIdx.x - NBE) * EPBA;
        for (int i = t; i < NRANGE; i += 256) hist[i] = 0;
        __syncthreads();
        #pragma unroll 4
        for (int k = 0; k < EPBA / 256; ++k) {
            int e = e0 + k * 256 + t;
            if (e < N_EDGES) atomicAdd(&hist[src[e] >> 6], 1);
        }
        __syncthreads();
        for (int i = t; i < NRANGE; i += 256) {
            int h = hist[i];
            base[i] = h ? atomicAdd(&gcur[i], h) : 0;
        }
        __syncthreads();
        for (int i = t; i < NRANGE; i += 256) hist[i] = 0;
        __syncthreads();
        #pragma unroll 4
        for (int k = 0; k < EPBA / 256; ++k) {
            int e = e0 + k * 256 + t;
            if (e < N_EDGES) {
                int s = src[e], d = dst[e];
                int r = s >> 6;
                int p = base[r] + atomicAdd(&hist[r], 1);
                part[(size_t)r * PCAP + p] = ((u32)s << 16) | (u32)d;
            }
        }
        return;
    }

    // ---------------- encode path ----------------
    const int node0 = blockIdx.x * 128;
    int nrem = N_NODES - node0; if (nrem > 128) nrem = 128;
    const int lane = t & 63, wid = t >> 6;
    const int l31 = lane & 31, hh = lane >> 5;
    const int nloc = wid * 32 + l31;
    const int sw7 = l31 & 7;

    // stage x (f32->bf16, swizzled) + enc weights
    #pragma unroll
    for (int it = 0; it < 8; ++it) {
        int idx = it * 256 + t;
        int nd = idx >> 4, s = idx & 15;
        float4 v0 = make_float4(0, 0, 0, 0), v1 = v0;
        if (nd < nrem) {
            const float4* px = (const float4*)(x + (size_t)(node0 + nd) * 128 + s * 8);
            v0 = px[0]; v1 = px[1];
        }
        uint4 w;
        w.x = pkbf(v0.x, v0.y); w.y = pkbf(v0.z, v0.w);
        w.z = pkbf(v1.x, v1.y); w.w = pkbf(v1.z, v1.w);
        LB[nd * 16 + (s ^ (nd & 7))] = w;
        LW[idx] = WtE[idx];
    }
    __syncthreads();

    const char* lb = (const char*)LB;
    const char* lw = (const char*)LW;

    // GEMM1: h^T = encW^T x^T  (D rows = h-cols, cols = nodes)
    f32x16 a0 = {}, a1 = {}, a2 = {}, a3 = {};
    #pragma unroll
    for (int r = 0; r < 16; ++r) {
        int rr = (r & 3) + 8 * (r >> 2) + 4 * hh;
        a0[r] = enc_b[rr];      a1[r] = enc_b[32 + rr];
        a2[r] = enc_b[64 + rr]; a3[r] = enc_b[96 + rr];
    }
    #pragma unroll
    for (int ks = 0; ks < 8; ++ks) {
        int so = ((ks * 2 + hh) ^ sw7) << 4;
        s16x8 bf = *(const s16x8*)(lb + nloc * 256 + so);
        s16x8 w0 = *(const s16x8*)(lw + l31 * 256 + so);
        s16x8 w1 = *(const s16x8*)(lw + 8192 + l31 * 256 + so);
        s16x8 w2 = *(const s16x8*)(lw + 16384 + l31 * 256 + so);
        s16x8 w3 = *(const s16x8*)(lw + 24576 + l31 * 256 + so);
        a0 = __builtin_amdgcn_mfma_f32_32x32x16_bf16(w0, bf, a0, 0, 0, 0);
        a1 = __builtin_amdgcn_mfma_f32_32x32x16_bf16(w1, bf, a1, 0, 0, 0);
        a2 = __builtin_amdgcn_mfma_f32_32x32x16_bf16(w2, bf, a2, 0, 0, 0);
        a3 = __builtin_amdgcn_mfma_f32_32x32x16_bf16(w3, bf, a3, 0, 0, 0);
    }

    // h^T -> in-register bf16 fragments (k = h-col)
    uint4 hf[8];
    BUILDF(hf[0], a0, 0, hh); BUILDF(hf[1], a0, 1, hh);
    BUILDF(hf[2], a1, 0, hh); BUILDF(hf[3], a1, 1, hh);
    BUILDF(hf[4], a2, 0, hh); BUILDF(hf[5], a2, 1, hh);
    BUILDF(hf[6], a3, 0, hh); BUILDF(hf[7], a3, 1, hh);

    // h rows -> global (pre-swizzled bf16 rows)
    if (nloc < nrem) {
        const size_t rb = (size_t)(node0 + nloc) * 16;
        #pragma unroll
        for (int f = 0; f < 8; ++f) {
            int g = 2 * f + hh;
            h_g[rb + (g ^ sw7)] = hf[f];
        }
    }

    __syncthreads();   // done reading WtE / x tile
    #pragma unroll
    for (int it = 0; it < 8; ++it) LW[it * 256 + t] = WtM[it * 256 + t];
    {   // sigWt (8KB) into LS
        uint4* LSu = (uint4*)LS;
        LSu[t] = WtS[t]; LSu[256 + t] = WtS[256 + t];
    }
    __syncthreads();

    // GEMM2: msg^T = msgW^T h^T  (B-operand = in-reg h frags)
    f32x16 m0 = {}, m1 = {}, m2 = {}, m3 = {};
    #pragma unroll
    for (int r = 0; r < 16; ++r) {
        int rr = (r & 3) + 8 * (r >> 2) + 4 * hh;
        m0[r] = msg_b[rr];      m1[r] = msg_b[32 + rr];
        m2[r] = msg_b[64 + rr]; m3[r] = msg_b[96 + rr];
    }
    #pragma unroll
    for (int ks = 0; ks < 8; ++ks) {
        int so = ((ks * 2 + hh) ^ sw7) << 4;
        U16B hb; hb.u = hf[ks];
        s16x8 w0 = *(const s16x8*)(lw + l31 * 256 + so);
        s16x8 w1 = *(const s16x8*)(lw + 8192 + l31 * 256 + so);
        s16x8 w2 = *(const s16x8*)(lw + 16384 + l31 * 256 + so);
        s16x8 w3 = *(const s16x8*)(lw + 24576 + l31 * 256 + so);
        m0 = __builtin_amdgcn_mfma_f32_32x32x16_bf16(w0, hb.s, m0, 0, 0, 0);
        m1 = __builtin_amdgcn_mfma_f32_32x32x16_bf16(w1, hb.s, m1, 0, 0, 0);
        m2 = __builtin_amdgcn_mfma_f32_32x32x16_bf16(w2, hb.s, m2, 0, 0, 0);
        m3 = __builtin_amdgcn_mfma_f32_32x32x16_bf16(w3, hb.s, m3, 0, 0, 0);
    }
    {   // relu + store msg rows (LINEAR layout)
        uint4 mf[8];
        BUILDR(mf[0], m0, 0, hh); BUILDR(mf[1], m0, 1, hh);
        BUILDR(mf[2], m1, 0, hh); BUILDR(mf[3], m1, 1, hh);
        BUILDR(mf[4], m2, 0, hh); BUILDR(mf[5], m2, 1, hh);
        BUILDR(mf[6], m3, 0, hh); BUILDR(mf[7], m3, 1, hh);
        if (nloc < nrem) {
            const size_t rb = (size_t)(node0 + nloc) * 16;
            #pragma unroll
            for (int f = 0; f < 8; ++f) {
                int g = 2 * f + hh;
                msg_g[rb + g] = mf[f];
            }
        }
    }

    // GEMM3: sig^T = sigW^T h^T  (rows 16..31 of sigWt are zero)
    f32x16 sg = {};
    #pragma unroll
    for (int r = 0; r < 8; ++r) {
        int rr = (r & 3) + 8 * (r >> 2) + 4 * hh;   // < 16
        sg[r] = sig_b[rr];
    }
    const char* lsw = (const char*)LS;
    #pragma unroll
    for (int ks = 0; ks < 8; ++ks) {
        int so = ((ks * 2 + hh) ^ sw7) << 4;
        s16x8 aw = *(const s16x8*)(lsw + l31 * 256 + so);
        U16B hb; hb.u = hf[ks];
        sg = __builtin_amdgcn_mfma_f32_32x32x16_bf16(aw, hb.s, sg, 0, 0, 0);
    }
    float ss = 0.f;
    #pragma unroll
    for (int r = 0; r < 8; ++r) ss += sg[r] * sg[r];
    ss += __shfl_xor(ss, 32);
    float inv = 1.0f / fmaxf(sqrtf(ss), 1e-12f);
    __syncthreads();   // all sigWt reads done before funnel overwrite
    #pragma unroll
    for (int r = 0; r < 8; ++r) {
        int sc = (r & 3) + 8 * (r >> 2) + 4 * hh;
        LS[nloc * 17 + sc] = sg[r] * inv;
    }
    __syncthreads();
    // sig rows -> global as bf16 pairs (8 u32 per node)
    #pragma unroll
    for (int it = 0; it < 4; ++it) {
        int idx = it * 256 + t;           // 1024 = 128 nodes x 8 u32
        int nd = idx >> 3, c2 = idx & 7;
        if (nd < nrem)
            sig_bf[(size_t)(node0 + nd) * 8 + c2] =
                pkbf(LS[nd * 17 + 2 * c2], LS[nd * 17 + 2 * c2 + 1]);
    }
}

// ---------------------------------------------------------------------------
// decode (MFMA): out = relu([h|comm]@agg_w+b) @ dec_w + b
// Block = 64 nodes, 4 waves: wave = (node half) x (64 col half).
// ---------------------------------------------------------------------------
__global__ __launch_bounds__(256) void k_decode_m(
    const uint4* __restrict__ h_g, const uint4* __restrict__ comm,
    const uint4* __restrict__ WtA0, const uint4* __restrict__ WtA1,
    const uint4* __restrict__ WtD,
    const float* __restrict__ agg_b, const float* __restrict__ dec_b,
    float* __restrict__ out)
{
    __shared__ uint4 LB[2048];   // Bcat [64][32 granules]; later Lcomb [64][16]
    __shared__ uint4 LW[2048];

    const int t = threadIdx.x;
    const int node0 = blockIdx.x * 64;
    int nrem = N_NODES - node0; if (nrem > 64) nrem = 64;
    const int lane = t & 63, wid = t >> 6;
    const int l31 = lane & 31, hh = lane >> 5;
    const int ng = wid & 1, cp = wid >> 1;
    const int nloc = ng * 32 + l31;
    const int sw7 = l31 & 7;

    // stage Bcat = [h | comm] bf16 (both pre-swizzled: linear copy)
    #pragma unroll
    for (int it = 0; it < 8; ++it) {
        int idx = it * 256 + t;
        int nd = idx >> 5, g = idx & 31;
        uint4 v = make_uint4(0, 0, 0, 0);
        if (nd < nrem)
            v = (g < 16) ? h_g[(size_t)(node0 + nd) * 16 + g]
                         : comm[(size_t)(node0 + nd) * 16 + (g - 16)];
        LB[nd * 32 + g] = v;
        LW[idx] = WtA0[idx];
    }
    __syncthreads();

    const char* lb = (const char*)LB;
    const char* lw = (const char*)LW;

    // GEMM-A: combined^T = aggW^T [h|comm]^T  (K = 256, staged in halves)
    f32x16 c0 = {}, c1 = {};
    #pragma unroll
    for (int r = 0; r < 16; ++r) {
        int rr = (r & 3) + 8 * (r >> 2) + 4 * hh;
        c0[r] = agg_b[cp * 64 + rr];
        c1[r] = agg_b[cp * 64 + 32 + rr];
    }
    #pragma unroll
    for (int ks = 0; ks < 8; ++ks) {
        int so = ((ks * 2 + hh) ^ sw7) << 4;
        s16x8 bf = *(const s16x8*)(lb + nloc * 512 + so);
        s16x8 w0 = *(const s16x8*)(lw + (cp * 64 + l31) * 256 + so);
        s16x8 w1 = *(const s16x8*)(lw + (cp * 64 + 32 + l31) * 256 + so);
        c0 = __builtin_amdgcn_mfma_f32_32x32x16_bf16(w0, bf, c0, 0, 0, 0);
        c1 = __builtin_amdgcn_mfma_f32_32x32x16_bf16(w1, bf, c1, 0, 0, 0);
    }
    __syncthreads();
    #pragma unroll
    for (int it = 0; it < 8; ++it) LW[it * 256 + t] = WtA1[it * 256 + t];
    __syncthreads();
    #pragma unroll
    for (int ks = 8; ks < 16; ++ks) {
        int so = ((ks * 2 + hh) ^ sw7) << 4;            // bit4 kept: comm half
        int so2 = (((ks - 8) * 2 + hh) ^ sw7) << 4;
        s16x8 bf = *(const s16x8*)(lb + nloc * 512 + so);
        s16x8 w0 = *(const s16x8*)(lw + (cp * 64 + l31) * 256 + so2);
        s16x8 w1 = *(const s16x8*)(lw + (cp * 64 + 32 + l31) * 256 + so2);
        c0 = __builtin_amdgcn_mfma_f32_32x32x16_bf16(w0, bf, c0, 0, 0, 0);
        c1 = __builtin_amdgcn_mfma_f32_32x32x16_bf16(w1, bf, c1, 0, 0, 0);
    }
    __syncthreads();   // all Bcat / WtA1 reads done

    // relu + build combined fragments; exchange across waves via LB (Lcomb)
    {
        uint4 cf[4];
        BUILDR(cf[0], c0, 0, hh); BUILDR(cf[1], c0, 1, hh);
        BUILDR(cf[2], c1, 0, hh); BUILDR(cf[3], c1, 1, hh);
        #pragma unroll
        for (int f = 0; f < 4; ++f) {
            int g = (cp * 4 + f) * 2 + hh;
            LB[nloc * 16 + (g ^ sw7)] = cf[f];
        }
    }
    #pragma unroll
    for (int it = 0; it < 8; ++it) LW[it * 256 + t] = WtD[it * 256 + t];
    __syncthreads();

    // GEMM-B: out = combined @ dec_w  (A = in-LDS combined frags, lane = outcol)
    f32x16 o0 = {}, o1 = {};
    {
        float b0 = dec_b[cp * 64 + l31], b1 = dec_b[cp * 64 + 32 + l31];
        #pragma unroll
        for (int r = 0; r < 16; ++r) { o0[r] = b0; o1[r] = b1; }
    }
    #pragma unroll
    for (int ks = 0; ks < 8; ++ks) {
        int so = ((ks * 2 + hh) ^ sw7) << 4;
        s16x8 af = *(const s16x8*)(lb + nloc * 256 + so);
        s16x8 w0 = *(const s16x8*)(lw + (cp * 64 + l31) * 256 + so);
        s16x8 w1 = *(const s16x8*)(lw + (cp * 64 + 32 + l31) * 256 + so);
        o0 = __builtin_amdgcn_mfma_f32_32x32x16_bf16(af, w0, o0, 0, 0, 0);
        o1 = __builtin_amdgcn_mfma_f32_32x32x16_bf16(af, w1, o1, 0, 0, 0);
    }
    #pragma unroll
    for (int r = 0; r < 16; ++r) {
        int nd = ng * 32 + (r & 3) + 8 * (r >> 2) + 4 * hh;
        if (nd < nrem) {
            float* row = out + (size_t)(node0 + nd) * 128 + cp * 64;
            row[l31]      = o0[r];
            row[32 + l31] = o1[r];
        }
    }
}

// ---------------------------------------------------------------------------
// fused partB + aggr, dst-chunk-sorted: one block per 64-node range.
//  pass 1: count entries per (node, chunk)   (chunk = dst/12500, 4 chunks)
//  prefix: per-node chunk bases (chunk-major layout within CAP region)
//  pass 2: e = exp(sig.sig); place (d,e) chunk-sorted; den via LDS atomics
//  PV:     2 nodes/wave (half-wave, lane = 4 dims); gathers sweep msg in
//          3.2MB chunks -> per-XCD L2 resident across co-resident blocks.
// ---------------------------------------------------------------------------
__global__ __launch_bounds__(256) void k_pb_aggr(
    const int* __restrict__ gcur, const u32* __restrict__ part,
    const u32* __restrict__ sig_bf,
    const char* __restrict__ msg_g, char* __restrict__ comm)
{
    __shared__ int   cnt4[64 * NCHUNK];  // per (node,chunk) count -> cursor
    __shared__ int   ctot[64];
    __shared__ float lden[64];
    __shared__ int2  lde[64 * CAP];      // 32 KB (d, e) pairs, chunk-major

    const int t = threadIdx.x;
    const int r = blockIdx.x;
    const int node0 = r * 64;

    for (int i = t; i < 64 * NCHUNK; i += 256) cnt4[i] = 0;
    if (t < 64) lden[t] = 0.f;
    __syncthreads();

    const int total = gcur[r];
    // pass 1: histogram per (node, chunk)
    for (int i = t; i < total; i += 256) {
        u32 en = part[(size_t)r * PCAP + i];
        int sl = (int)((en >> 16) & 63);
        int c  = (int)((en & 0xFFFFu) / 12500u);
        atomicAdd(&cnt4[sl * NCHUNK + c], 1);
    }
    __syncthreads();
    if (t < 64) {
        int b = 0;
        #pragma unroll
        for (int c = 0; c < NCHUNK; ++c) {
            int v = cnt4[t * NCHUNK + c];
            cnt4[t * NCHUNK + c] = b;
            b += v;
        }
        ctot[t] = b;
    }
    __syncthreads();
    // pass 2: score + chunk-sorted placement
    for (int i = t; i < total; i += 256) {
        u32 en = part[(size_t)r * PCAP + i];
        int s = (int)(en >> 16), d = (int)(en & 0xFFFFu);
        const uint4* ps = (const uint4*)(sig_bf + (size_t)s * 8);
        const uint4* pd = (const uint4*)(sig_bf + (size_t)d * 8);
        uint4 sa = ps[0], sb = ps[1];
        uint4 da = pd[0], db = pd[1];
        float dot = dotpair(sa.x, da.x) + dotpair(sa.y, da.y)
                  + dotpair(sa.z, da.z) + dotpair(sa.w, da.w)
                  + dotpair(sb.x, db.x) + dotpair(sb.y, db.y)
                  + dotpair(sb.z, db.z) + dotpair(sb.w, db.w);
        float e = __expf(dot);   // |dot|<=1 (unit sigs): segment_max elision exact
        int sl = s & 63;
        int c  = d / 12500;
        int p  = atomicAdd(&cnt4[sl * NCHUNK + c], 1);
        lde[sl * CAP + p] = make_int2(d, __float_as_int(e));
        atomicAdd(&lden[sl], e);
    }
    __syncthreads();

    // PV: wave wid covers nodes [wid*16, wid*16+16), 2 at a time (half-waves)
    const int lane = t & 63, wid = t >> 6;
    const int l31 = lane & 31, hh = lane >> 5;
    #pragma unroll
    for (int g = 0; g < 8; ++g) {
        const int nloc = wid * 16 + 2 * g + hh;
        const int node = node0 + nloc;
        const int cn = ctot[nloc];
        float a0 = 0.f, a1 = 0.f, a2 = 0.f, a3 = 0.f;
        for (int k = 0; k < cn; ++k) {
            int2 de = lde[nloc * CAP + k];
            float e = __int_as_float(de.y);
            uint2 m = *(const uint2*)(msg_g + (size_t)de.x * 256 + 8 * l31);
            a0 += e * bf2f(m.x & 0xFFFFu);
            a1 += e * bf2f(m.x >> 16);
            a2 += e * bf2f(m.y & 0xFFFFu);
            a3 += e * bf2f(m.y >> 16);
        }
        float den = lden[nloc];
        float inv = (den > 0.f) ? (1.0f / den) : 0.f;
        if (node < N_NODES) {
            uint2 w;
            w.x = pkbf(a0 * inv, a1 * inv);
            w.y = pkbf(a2 * inv, a3 * inv);
            *(uint2*)(comm + (size_t)node * 256 + ((8 * l31) ^ ((node & 7) << 4))) = w;
        }
    }
}

// ---------------------------------------------------------------------------
extern "C" void kernel_launch(void* const* d_in, const int* in_sizes, int n_in,
                              void* d_out, int out_size, void* d_ws, size_t ws_size,
                              hipStream_t stream)
{
    const float* x     = (const float*)d_in[0];
    const int*   ei    = (const int*)  d_in[1];
    const float* enc_w = (const float*)d_in[2];
    const float* enc_b = (const float*)d_in[3];
    const float* sig_w = (const float*)d_in[4];
    const float* sig_b = (const float*)d_in[5];
    const float* msg_w = (const float*)d_in[6];
    const float* msg_b = (const float*)d_in[7];
    const float* agg_w = (const float*)d_in[8];
    const float* agg_b = (const float*)d_in[9];
    const float* dec_w = (const float*)d_in[10];
    const float* dec_b = (const float*)d_in[11];
    float* out = (float*)d_out;

    const int* src = ei;            // edge_index[0]
    const int* dst = ei + N_EDGES;  // edge_index[1]

    // workspace layout (bytes), ~45 MB
    char* p = (char*)d_ws;
    uint4* h_g   = (uint4*)p;  p += (size_t)N_NODES * 256;  // bf16 rows, swizzled
    uint4* msg_g = (uint4*)p;  p += (size_t)N_NODES * 256;  // bf16 rows, LINEAR
    uint4* comm  = (uint4*)p;  p += (size_t)N_NODES * 256;  // bf16 rows, swizzled
    u32*   sig_bf = (u32*)p;   p += (size_t)N_NODES * 32;   // bf16 sig rows
    u32*   part   = (u32*)p;   p += (size_t)NRANGE * PCAP * 4;
    int*   gcur   = (int*)p;   p += 4096;
    uint4* WtE  = (uint4*)p; p += 32768;
    uint4* WtM  = (uint4*)p; p += 32768;
    uint4* WtD  = (uint4*)p; p += 32768;
    uint4* WtA0 = (uint4*)p; p += 32768;
    uint4* WtA1 = (uint4*)p; p += 32768;
    uint4* WtS  = (uint4*)p; p += 8192;

    k_prep<<<42, 256, 0, stream>>>(enc_w, msg_w, sig_w, agg_w, dec_w,
                                   WtE, WtM, WtD, WtA0, WtA1, WtS, gcur);
    k_enc_part<<<NBE + NBA, 256, 0, stream>>>(
        x, WtE, WtM, WtS, enc_b, sig_b, msg_b, h_g, sig_bf, msg_g,
        src, dst, gcur, part);
    k_pb_aggr<<<NRANGE, 256, 0, stream>>>(
        gcur, part, sig_bf, (const char*)msg_g, (char*)comm);
    k_decode_m<<<(N_NODES + 63) / 64, 256, 0, stream>>>(
        h_g, comm, WtA0, WtA1, WtD, agg_b, dec_b, out);
}

// Round 15
// 95.788 us; speedup vs baseline: 1.5062x; 1.0623x over previous
//
#include <hip/hip_runtime.h>
#include <math.h>

#define N_NODES 50000
#define N_EDGES 800000
#define CAP 64     // bucket capacity per node (max degree <= 64, validated r7-r14)
#define NRANGE 782 // ceil(N_NODES/64) ranges of 64 nodes
#define PCAP 1280  // part capacity per range (mean 1023, +8 sigma)
#define EPBA 2560  // edges per partA block
#define NBA 313    // ceil(N_EDGES/EPBA)
#define NBE 391    // encode blocks: ceil(50000/128)

typedef __attribute__((ext_vector_type(8)))  short s16x8;   // 8 bf16 (4 VGPR)
typedef __attribute__((ext_vector_type(16))) float f32x16;  // MFMA acc
typedef unsigned int u32;
typedef unsigned short u16;

union U16B { uint4 u; s16x8 s; };

// f32 -> bf16 bits, round-to-nearest-even
__device__ __forceinline__ u32 bfr(float f) {
    u32 u = __float_as_uint(f);
    return (u + 0x7FFFu + ((u >> 16) & 1u)) >> 16;
}
__device__ __forceinline__ u32 pkbf(float a, float b) { return bfr(a) | (bfr(b) << 16); }
__device__ __forceinline__ float bf2f(u32 b) { return __uint_as_float(b << 16); }
// dot of a bf16x2 pair against another
__device__ __forceinline__ float dotpair(u32 a, u32 b) {
    return bf2f(a & 0xFFFFu) * bf2f(b & 0xFFFFu) + bf2f(a >> 16) * bf2f(b >> 16);
}

// Build an MFMA input frag (lane-dim = D-col, k = 8*(lane>>5)+e) from 8 f32
// D-regs of a 32x32x16 accumulator (rows (r&3)+8*(r>>2)+4*hh), via bf16 pack
// + half-wave exchange. d8 must be compile-time indexed by caller.
__device__ __forceinline__ uint4 buildfrag(const float* d8, int hh) {
    u32 P = pkbf(d8[0], d8[1]), Q = pkbf(d8[2], d8[3]);
    u32 R = pkbf(d8[4], d8[5]), S = pkbf(d8[6], d8[7]);
    u32 sP = (u32)__shfl_xor((int)P, 32);
    u32 sQ = (u32)__shfl_xor((int)Q, 32);
    u32 sR = (u32)__shfl_xor((int)R, 32);
    u32 sS = (u32)__shfl_xor((int)S, 32);
    uint4 f;
    f.x = hh ? sR : P;  f.y = hh ? sS : Q;
    f.z = hh ? R : sP;  f.w = hh ? S : sQ;
    return f;
}
#define BUILDF(OUT, ACC, Q, HH) do { \
    float _td[8]; \
    _Pragma("unroll") for (int _z = 0; _z < 8; ++_z) _td[_z] = (ACC)[(Q)*8 + _z]; \
    (OUT) = buildfrag(_td, HH); } while (0)
#define BUILDR(OUT, ACC, Q, HH) do { \
    float _td[8]; \
    _Pragma("unroll") for (int _z = 0; _z < 8; ++_z) _td[_z] = fmaxf((ACC)[(Q)*8 + _z], 0.f); \
    (OUT) = buildfrag(_td, HH); } while (0)

// ---------------------------------------------------------------------------
// prep: weights -> bf16, transposed [col][k] rows (256B), granule-XOR swizzled
// Also zeroes gcur (saves the memset dispatch).
// ---------------------------------------------------------------------------
__global__ __launch_bounds__(256) void k_prep(
    const float* __restrict__ enc_w, const float* __restrict__ msg_w,
    const float* __restrict__ sig_w, const float* __restrict__ agg_w,
    const float* __restrict__ dec_w,
    uint4* __restrict__ WtE, uint4* __restrict__ WtM, uint4* __restrict__ WtD,
    uint4* __restrict__ WtA0, uint4* __restrict__ WtA1, uint4* __restrict__ WtS,
    int* __restrict__ gcur)
{
    int gid = blockIdx.x * 256 + threadIdx.x;
    if (gid < NRANGE) gcur[gid] = 0;
    if (gid < 10240) {
        int m = gid >> 11, r = gid & 2047;
        int col = r >> 4, s = r & 15;
        const float* W; uint4* D; int kb = 0;
        if      (m == 0) { W = enc_w; D = WtE; }
        else if (m == 1) { W = msg_w; D = WtM; }
        else if (m == 2) { W = dec_w; D = WtD; }
        else if (m == 3) { W = agg_w; D = WtA0; }
        else             { W = agg_w; D = WtA1; kb = 128; }
        float v[8];
        #pragma unroll
        for (int j = 0; j < 8; ++j) v[j] = W[(size_t)(kb + s * 8 + j) * 128 + col];
        uint4 w;
        w.x = pkbf(v[0], v[1]); w.y = pkbf(v[2], v[3]);
        w.z = pkbf(v[4], v[5]); w.w = pkbf(v[6], v[7]);
        D[col * 16 + (s ^ (col & 7))] = w;
    } else if (gid < 10752) {
        int r = gid - 10240;
        int row = r >> 4, s = r & 15;
        float v[8];
        #pragma unroll
        for (int j = 0; j < 8; ++j)
            v[j] = (row < 16) ? sig_w[(size_t)(s * 8 + j) * 16 + row] : 0.0f;
        uint4 w;
        w.x = pkbf(v[0], v[1]); w.y = pkbf(v[2], v[3]);
        w.z = pkbf(v[4], v[5]); w.w = pkbf(v[6], v[7]);
        WtS[row * 16 + (s ^ (row & 7))] = w;
    }
}

// ---------------------------------------------------------------------------
// fused encode + partA. Encode reads weight fragments DIRECTLY from global
// (L2-resident, same swizzled index math as before) -> LDS = 41 KB -> 3
// blocks/CU. partA split into 313 small blocks so its tail co-runs fully.
//   blockIdx <  NBE : MFMA encode (h, msg, sig)
//   blockIdx >= NBE : LDS radix partition of edges by range r = src>>6
// ---------------------------------------------------------------------------
__global__ __launch_bounds__(256) void k_enc_part(
    const float* __restrict__ x,
    const uint4* __restrict__ WtE, const uint4* __restrict__ WtM,
    const uint4* __restrict__ WtS,
    const float* __restrict__ enc_b, const float* __restrict__ sig_b,
    const float* __restrict__ msg_b,
    uint4* __restrict__ h_g, u32* __restrict__ sig_bf, uint4* __restrict__ msg_g,
    const int* __restrict__ src, const int* __restrict__ dst,
    int* __restrict__ gcur, u32* __restrict__ part)
{
    __shared__ uint4 LB[2048];   // x tile bf16 [128 nodes][16 gran] / partA hist+base
    __shared__ float LS[2176];   // sig funnel

    const int t = threadIdx.x;

    if (blockIdx.x >= NBE) {
        // ---------------- partA path ----------------
        int* hist = (int*)LB;
        int* base = hist + NRANGE;
        const int e0 = (blockIdx.x - NBE) * EPBA;
        for (int i = t; i < NRANGE; i += 256) hist[i] = 0;
        __syncthreads();
        #pragma unroll 4
        for (int k = 0; k < EPBA / 256; ++k) {
            int e = e0 + k * 256 + t;
            if (e < N_EDGES) atomicAdd(&hist[src[e] >> 6], 1);
        }
        __syncthreads();
        for (int i = t; i < NRANGE; i += 256) {
            int h = hist[i];
            base[i] = h ? atomicAdd(&gcur[i], h) : 0;
        }
        __syncthreads();
        for (int i = t; i < NRANGE; i += 256) hist[i] = 0;
        __syncthreads();
        #pragma unroll 4
        for (int k = 0; k < EPBA / 256; ++k) {
            int e = e0 + k * 256 + t;
            if (e < N_EDGES) {
                int s = src[e], d = dst[e];
                int r = s >> 6;
                int p = base[r] + atomicAdd(&hist[r], 1);
                part[(size_t)r * PCAP + p] = ((u32)s << 16) | (u32)d;
            }
        }
        return;
    }

    // ---------------- encode path ----------------
    const int node0 = blockIdx.x * 128;
    int nrem = N_NODES - node0; if (nrem > 128) nrem = 128;
    const int lane = t & 63, wid = t >> 6;
    const int l31 = lane & 31, hh = lane >> 5;
    const int nloc = wid * 32 + l31;
    const int sw7 = l31 & 7;

    // stage x (f32->bf16, swizzled)
    #pragma unroll
    for (int it = 0; it < 8; ++it) {
        int idx = it * 256 + t;
        int nd = idx >> 4, s = idx & 15;
        float4 v0 = make_float4(0, 0, 0, 0), v1 = v0;
        if (nd < nrem) {
            const float4* px = (const float4*)(x + (size_t)(node0 + nd) * 128 + s * 8);
            v0 = px[0]; v1 = px[1];
        }
        uint4 w;
        w.x = pkbf(v0.x, v0.y); w.y = pkbf(v0.z, v0.w);
        w.z = pkbf(v1.x, v1.y); w.w = pkbf(v1.z, v1.w);
        LB[nd * 16 + (s ^ (nd & 7))] = w;
    }
    __syncthreads();

    const char* lb = (const char*)LB;
    const char* gwE = (const char*)WtE;
    const char* gwM = (const char*)WtM;
    const char* gwS = (const char*)WtS;

    // GEMM1: h^T = encW^T x^T  (weights direct from global, L2-resident)
    f32x16 a0 = {}, a1 = {}, a2 = {}, a3 = {};
    #pragma unroll
    for (int r = 0; r < 16; ++r) {
        int rr = (r & 3) + 8 * (r >> 2) + 4 * hh;
        a0[r] = enc_b[rr];      a1[r] = enc_b[32 + rr];
        a2[r] = enc_b[64 + rr]; a3[r] = enc_b[96 + rr];
    }
    #pragma unroll
    for (int ks = 0; ks < 8; ++ks) {
        int so = ((ks * 2 + hh) ^ sw7) << 4;
        s16x8 bf = *(const s16x8*)(lb + nloc * 256 + so);
        s16x8 w0 = *(const s16x8*)(gwE + l31 * 256 + so);
        s16x8 w1 = *(const s16x8*)(gwE + 8192 + l31 * 256 + so);
        s16x8 w2 = *(const s16x8*)(gwE + 16384 + l31 * 256 + so);
        s16x8 w3 = *(const s16x8*)(gwE + 24576 + l31 * 256 + so);
        a0 = __builtin_amdgcn_mfma_f32_32x32x16_bf16(w0, bf, a0, 0, 0, 0);
        a1 = __builtin_amdgcn_mfma_f32_32x32x16_bf16(w1, bf, a1, 0, 0, 0);
        a2 = __builtin_amdgcn_mfma_f32_32x32x16_bf16(w2, bf, a2, 0, 0, 0);
        a3 = __builtin_amdgcn_mfma_f32_32x32x16_bf16(w3, bf, a3, 0, 0, 0);
    }

    // h^T -> in-register bf16 fragments (k = h-col)
    uint4 hf[8];
    BUILDF(hf[0], a0, 0, hh); BUILDF(hf[1], a0, 1, hh);
    BUILDF(hf[2], a1, 0, hh); BUILDF(hf[3], a1, 1, hh);
    BUILDF(hf[4], a2, 0, hh); BUILDF(hf[5], a2, 1, hh);
    BUILDF(hf[6], a3, 0, hh); BUILDF(hf[7], a3, 1, hh);

    // h rows -> global (pre-swizzled bf16 rows)
    if (nloc < nrem) {
        const size_t rb = (size_t)(node0 + nloc) * 16;
        #pragma unroll
        for (int f = 0; f < 8; ++f) {
            int g = 2 * f + hh;
            h_g[rb + (g ^ sw7)] = hf[f];
        }
    }

    // GEMM2: msg^T = msgW^T h^T  (B-operand = in-reg h frags)
    f32x16 m0 = {}, m1 = {}, m2 = {}, m3 = {};
    #pragma unroll
    for (int r = 0; r < 16; ++r) {
        int rr = (r & 3) + 8 * (r >> 2) + 4 * hh;
        m0[r] = msg_b[rr];      m1[r] = msg_b[32 + rr];
        m2[r] = msg_b[64 + rr]; m3[r] = msg_b[96 + rr];
    }
    #pragma unroll
    for (int ks = 0; ks < 8; ++ks) {
        int so = ((ks * 2 + hh) ^ sw7) << 4;
        U16B hb; hb.u = hf[ks];
        s16x8 w0 = *(const s16x8*)(gwM + l31 * 256 + so);
        s16x8 w1 = *(const s16x8*)(gwM + 8192 + l31 * 256 + so);
        s16x8 w2 = *(const s16x8*)(gwM + 16384 + l31 * 256 + so);
        s16x8 w3 = *(const s16x8*)(gwM + 24576 + l31 * 256 + so);
        m0 = __builtin_amdgcn_mfma_f32_32x32x16_bf16(w0, hb.s, m0, 0, 0, 0);
        m1 = __builtin_amdgcn_mfma_f32_32x32x16_bf16(w1, hb.s, m1, 0, 0, 0);
        m2 = __builtin_amdgcn_mfma_f32_32x32x16_bf16(w2, hb.s, m2, 0, 0, 0);
        m3 = __builtin_amdgcn_mfma_f32_32x32x16_bf16(w3, hb.s, m3, 0, 0, 0);
    }
    {   // relu + store msg rows (LINEAR layout)
        uint4 mf[8];
        BUILDR(mf[0], m0, 0, hh); BUILDR(mf[1], m0, 1, hh);
        BUILDR(mf[2], m1, 0, hh); BUILDR(mf[3], m1, 1, hh);
        BUILDR(mf[4], m2, 0, hh); BUILDR(mf[5], m2, 1, hh);
        BUILDR(mf[6], m3, 0, hh); BUILDR(mf[7], m3, 1, hh);
        if (nloc < nrem) {
            const size_t rb = (size_t)(node0 + nloc) * 16;
            #pragma unroll
            for (int f = 0; f < 8; ++f) {
                int g = 2 * f + hh;
                msg_g[rb + g] = mf[f];
            }
        }
    }

    // GEMM3: sig^T = sigW^T h^T  (rows 16..31 of sigWt are zero)
    f32x16 sg = {};
    #pragma unroll
    for (int r = 0; r < 8; ++r) {
        int rr = (r & 3) + 8 * (r >> 2) + 4 * hh;   // < 16
        sg[r] = sig_b[rr];
    }
    #pragma unroll
    for (int ks = 0; ks < 8; ++ks) {
        int so = ((ks * 2 + hh) ^ sw7) << 4;
        s16x8 aw = *(const s16x8*)(gwS + l31 * 256 + so);
        U16B hb; hb.u = hf[ks];
        sg = __builtin_amdgcn_mfma_f32_32x32x16_bf16(aw, hb.s, sg, 0, 0, 0);
    }
    float ss = 0.f;
    #pragma unroll
    for (int r = 0; r < 8; ++r) ss += sg[r] * sg[r];
    ss += __shfl_xor(ss, 32);
    float inv = 1.0f / fmaxf(sqrtf(ss), 1e-12f);
    #pragma unroll
    for (int r = 0; r < 8; ++r) {
        int sc = (r & 3) + 8 * (r >> 2) + 4 * hh;
        LS[nloc * 17 + sc] = sg[r] * inv;
    }
    __syncthreads();
    // sig rows -> global as bf16 pairs (8 u32 per node)
    #pragma unroll
    for (int it = 0; it < 4; ++it) {
        int idx = it * 256 + t;           // 1024 = 128 nodes x 8 u32
        int nd = idx >> 3, c2 = idx & 7;
        if (nd < nrem)
            sig_bf[(size_t)(node0 + nd) * 8 + c2] =
                pkbf(LS[nd * 17 + 2 * c2], LS[nd * 17 + 2 * c2 + 1]);
    }
}

// ---------------------------------------------------------------------------
// decode (MFMA): out = relu([h|comm]@agg_w+b) @ dec_w + b
// Block = 64 nodes, 4 waves: wave = (node half) x (64 col half).
// ---------------------------------------------------------------------------
__global__ __launch_bounds__(256) void k_decode_m(
    const uint4* __restrict__ h_g, const uint4* __restrict__ comm,
    const uint4* __restrict__ WtA0, const uint4* __restrict__ WtA1,
    const uint4* __restrict__ WtD,
    const float* __restrict__ agg_b, const float* __restrict__ dec_b,
    float* __restrict__ out)
{
    __shared__ uint4 LB[2048];   // Bcat [64][32 granules]; later Lcomb [64][16]
    __shared__ uint4 LW[2048];

    const int t = threadIdx.x;
    const int node0 = blockIdx.x * 64;
    int nrem = N_NODES - node0; if (nrem > 64) nrem = 64;
    const int lane = t & 63, wid = t >> 6;
    const int l31 = lane & 31, hh = lane >> 5;
    const int ng = wid & 1, cp = wid >> 1;
    const int nloc = ng * 32 + l31;
    const int sw7 = l31 & 7;

    // stage Bcat = [h | comm] bf16 (both pre-swizzled: linear copy)
    #pragma unroll
    for (int it = 0; it < 8; ++it) {
        int idx = it * 256 + t;
        int nd = idx >> 5, g = idx & 31;
        uint4 v = make_uint4(0, 0, 0, 0);
        if (nd < nrem)
            v = (g < 16) ? h_g[(size_t)(node0 + nd) * 16 + g]
                         : comm[(size_t)(node0 + nd) * 16 + (g - 16)];
        LB[nd * 32 + g] = v;
        LW[idx] = WtA0[idx];
    }
    __syncthreads();

    const char* lb = (const char*)LB;
    const char* lw = (const char*)LW;

    // GEMM-A: combined^T = aggW^T [h|comm]^T  (K = 256, staged in halves)
    f32x16 c0 = {}, c1 = {};
    #pragma unroll
    for (int r = 0; r < 16; ++r) {
        int rr = (r & 3) + 8 * (r >> 2) + 4 * hh;
        c0[r] = agg_b[cp * 64 + rr];
        c1[r] = agg_b[cp * 64 + 32 + rr];
    }
    #pragma unroll
    for (int ks = 0; ks < 8; ++ks) {
        int so = ((ks * 2 + hh) ^ sw7) << 4;
        s16x8 bf = *(const s16x8*)(lb + nloc * 512 + so);
        s16x8 w0 = *(const s16x8*)(lw + (cp * 64 + l31) * 256 + so);
        s16x8 w1 = *(const s16x8*)(lw + (cp * 64 + 32 + l31) * 256 + so);
        c0 = __builtin_amdgcn_mfma_f32_32x32x16_bf16(w0, bf, c0, 0, 0, 0);
        c1 = __builtin_amdgcn_mfma_f32_32x32x16_bf16(w1, bf, c1, 0, 0, 0);
    }
    __syncthreads();
    #pragma unroll
    for (int it = 0; it < 8; ++it) LW[it * 256 + t] = WtA1[it * 256 + t];
    __syncthreads();
    #pragma unroll
    for (int ks = 8; ks < 16; ++ks) {
        int so = ((ks * 2 + hh) ^ sw7) << 4;            // bit4 kept: comm half
        int so2 = (((ks - 8) * 2 + hh) ^ sw7) << 4;
        s16x8 bf = *(const s16x8*)(lb + nloc * 512 + so);
        s16x8 w0 = *(const s16x8*)(lw + (cp * 64 + l31) * 256 + so2);
        s16x8 w1 = *(const s16x8*)(lw + (cp * 64 + 32 + l31) * 256 + so2);
        c0 = __builtin_amdgcn_mfma_f32_32x32x16_bf16(w0, bf, c0, 0, 0, 0);
        c1 = __builtin_amdgcn_mfma_f32_32x32x16_bf16(w1, bf, c1, 0, 0, 0);
    }
    __syncthreads();   // all Bcat / WtA1 reads done

    // relu + build combined fragments; exchange across waves via LB (Lcomb)
    {
        uint4 cf[4];
        BUILDR(cf[0], c0, 0, hh); BUILDR(cf[1], c0, 1, hh);
        BUILDR(cf[2], c1, 0, hh); BUILDR(cf[3], c1, 1, hh);
        #pragma unroll
        for (int f = 0; f < 4; ++f) {
            int g = (cp * 4 + f) * 2 + hh;
            LB[nloc * 16 + (g ^ sw7)] = cf[f];
        }
    }
    #pragma unroll
    for (int it = 0; it < 8; ++it) LW[it * 256 + t] = WtD[it * 256 + t];
    __syncthreads();

    // GEMM-B: out = combined @ dec_w  (A = in-LDS combined frags, lane = outcol)
    f32x16 o0 = {}, o1 = {};
    {
        float b0 = dec_b[cp * 64 + l31], b1 = dec_b[cp * 64 + 32 + l31];
        #pragma unroll
        for (int r = 0; r < 16; ++r) { o0[r] = b0; o1[r] = b1; }
    }
    #pragma unroll
    for (int ks = 0; ks < 8; ++ks) {
        int so = ((ks * 2 + hh) ^ sw7) << 4;
        s16x8 af = *(const s16x8*)(lb + nloc * 256 + so);
        s16x8 w0 = *(const s16x8*)(lw + (cp * 64 + l31) * 256 + so);
        s16x8 w1 = *(const s16x8*)(lw + (cp * 64 + 32 + l31) * 256 + so);
        o0 = __builtin_amdgcn_mfma_f32_32x32x16_bf16(af, w0, o0, 0, 0, 0);
        o1 = __builtin_amdgcn_mfma_f32_32x32x16_bf16(af, w1, o1, 0, 0, 0);
    }
    #pragma unroll
    for (int r = 0; r < 16; ++r) {
        int nd = ng * 32 + (r & 3) + 8 * (r >> 2) + 4 * hh;
        if (nd < nrem) {
            float* row = out + (size_t)(node0 + nd) * 128 + cp * 64;
            row[l31]      = o0[r];
            row[32 + l31] = o1[r];
        }
    }
}

// ---------------------------------------------------------------------------
// fused partB + aggr: one block per 64-node range.
//  phase 1: bin entries into LDS (d, e=exp(sig.sig)) pairs; den via LDS atomics
//  phase 2: PV — 2 nodes/wave (half-wave, lane = 4 dims), 4-way unrolled with
//           batched independent gathers (4 outstanding L2 loads per half-wave).
// ---------------------------------------------------------------------------
__global__ __launch_bounds__(256) void k_pb_aggr(
    const int* __restrict__ gcur, const u32* __restrict__ part,
    const u32* __restrict__ sig_bf,
    const char* __restrict__ msg_g, char* __restrict__ comm)
{
    __shared__ int   cnt[64];
    __shared__ float lden[64];
    __shared__ int2  lde[64 * CAP];   // 32 KB (d, e) pairs

    const int t = threadIdx.x;
    const int r = blockIdx.x;
    const int node0 = r * 64;

    if (t < 64) { cnt[t] = 0; lden[t] = 0.f; }
    __syncthreads();

    const int total = gcur[r];
    for (int i = t; i < total; i += 256) {
        u32 en = part[(size_t)r * PCAP + i];
        int s = (int)(en >> 16), d = (int)(en & 0xFFFFu);
        const uint4* ps = (const uint4*)(sig_bf + (size_t)s * 8);
        const uint4* pd = (const uint4*)(sig_bf + (size_t)d * 8);
        uint4 sa = ps[0], sb = ps[1];
        uint4 da = pd[0], db = pd[1];
        float dot = dotpair(sa.x, da.x) + dotpair(sa.y, da.y)
                  + dotpair(sa.z, da.z) + dotpair(sa.w, da.w)
                  + dotpair(sb.x, db.x) + dotpair(sb.y, db.y)
                  + dotpair(sb.z, db.z) + dotpair(sb.w, db.w);
        float e = __expf(dot);   // |dot|<=1 (unit sigs): segment_max elision exact
        int sl = s & 63;
        int p = atomicAdd(&cnt[sl], 1);
        lde[sl * CAP + p] = make_int2(d, __float_as_int(e));
        atomicAdd(&lden[sl], e);
    }
    __syncthreads();

    // PV: wave wid covers nodes [wid*16, wid*16+16), 2 at a time (half-waves)
    const int lane = t & 63, wid = t >> 6;
    const int l31 = lane & 31, hh = lane >> 5;
    #pragma unroll
    for (int g = 0; g < 8; ++g) {
        const int nloc = wid * 16 + 2 * g + hh;
        const int node = node0 + nloc;
        const int cn = cnt[nloc];
        const int2* ld = &lde[nloc * CAP];
        float a0 = 0.f, a1 = 0.f, a2 = 0.f, a3 = 0.f;
        int k = 0;
        for (; k + 4 <= cn; k += 4) {
            int2 d0 = ld[k], d1 = ld[k + 1], d2 = ld[k + 2], d3 = ld[k + 3];
            uint2 m0 = *(const uint2*)(msg_g + (size_t)d0.x * 256 + 8 * l31);
            uint2 m1 = *(const uint2*)(msg_g + (size_t)d1.x * 256 + 8 * l31);
            uint2 m2 = *(const uint2*)(msg_g + (size_t)d2.x * 256 + 8 * l31);
            uint2 m3 = *(const uint2*)(msg_g + (size_t)d3.x * 256 + 8 * l31);
            float e0 = __int_as_float(d0.y), e1 = __int_as_float(d1.y);
            float e2 = __int_as_float(d2.y), e3 = __int_as_float(d3.y);
            a0 += e0 * bf2f(m0.x & 0xFFFFu); a1 += e0 * bf2f(m0.x >> 16);
            a2 += e0 * bf2f(m0.y & 0xFFFFu); a3 += e0 * bf2f(m0.y >> 16);
            a0 += e1 * bf2f(m1.x & 0xFFFFu); a1 += e1 * bf2f(m1.x >> 16);
            a2 += e1 * bf2f(m1.y & 0xFFFFu); a3 += e1 * bf2f(m1.y >> 16);
            a0 += e2 * bf2f(m2.x & 0xFFFFu); a1 += e2 * bf2f(m2.x >> 16);
            a2 += e2 * bf2f(m2.y & 0xFFFFu); a3 += e2 * bf2f(m2.y >> 16);
            a0 += e3 * bf2f(m3.x & 0xFFFFu); a1 += e3 * bf2f(m3.x >> 16);
            a2 += e3 * bf2f(m3.y & 0xFFFFu); a3 += e3 * bf2f(m3.y >> 16);
        }
        for (; k < cn; ++k) {
            int2 de = ld[k];
            float e = __int_as_float(de.y);
            uint2 m = *(const uint2*)(msg_g + (size_t)de.x * 256 + 8 * l31);
            a0 += e * bf2f(m.x & 0xFFFFu);
            a1 += e * bf2f(m.x >> 16);
            a2 += e * bf2f(m.y & 0xFFFFu);
            a3 += e * bf2f(m.y >> 16);
        }
        float den = lden[nloc];
        float inv = (den > 0.f) ? (1.0f / den) : 0.f;
        if (node < N_NODES) {
            uint2 w;
            w.x = pkbf(a0 * inv, a1 * inv);
            w.y = pkbf(a2 * inv, a3 * inv);
            *(uint2*)(comm + (size_t)node * 256 + ((8 * l31) ^ ((node & 7) << 4))) = w;
        }
    }
}

// ---------------------------------------------------------------------------
extern "C" void kernel_launch(void* const* d_in, const int* in_sizes, int n_in,
                              void* d_out, int out_size, void* d_ws, size_t ws_size,
                              hipStream_t stream)
{
    const float* x     = (const float*)d_in[0];
    const int*   ei    = (const int*)  d_in[1];
    const float* enc_w = (const float*)d_in[2];
    const float* enc_b = (const float*)d_in[3];
    const float* sig_w = (const float*)d_in[4];
    const float* sig_b = (const float*)d_in[5];
    const float* msg_w = (const float*)d_in[6];
    const float* msg_b = (const float*)d_in[7];
    const float* agg_w = (const float*)d_in[8];
    const float* agg_b = (const float*)d_in[9];
    const float* dec_w = (const float*)d_in[10];
    const float* dec_b = (const float*)d_in[11];
    float* out = (float*)d_out;

    const int* src = ei;            // edge_index[0]
    const int* dst = ei + N_EDGES;  // edge_index[1]

    // workspace layout (bytes), ~45 MB
    char* p = (char*)d_ws;
    uint4* h_g   = (uint4*)p;  p += (size_t)N_NODES * 256;  // bf16 rows, swizzled
    uint4* msg_g = (uint4*)p;  p += (size_t)N_NODES * 256;  // bf16 rows, LINEAR
    uint4* comm  = (uint4*)p;  p += (size_t)N_NODES * 256;  // bf16 rows, swizzled
    u32*   sig_bf = (u32*)p;   p += (size_t)N_NODES * 32;   // bf16 sig rows
    u32*   part   = (u32*)p;   p += (size_t)NRANGE * PCAP * 4;
    int*   gcur   = (int*)p;   p += 4096;
    uint4* WtE  = (uint4*)p; p += 32768;
    uint4* WtM  = (uint4*)p; p += 32768;
    uint4* WtD  = (uint4*)p; p += 32768;
    uint4* WtA0 = (uint4*)p; p += 32768;
    uint4* WtA1 = (uint4*)p; p += 32768;
    uint4* WtS  = (uint4*)p; p += 8192;

    k_prep<<<42, 256, 0, stream>>>(enc_w, msg_w, sig_w, agg_w, dec_w,
                                   WtE, WtM, WtD, WtA0, WtA1, WtS, gcur);
    k_enc_part<<<NBE + NBA, 256, 0, stream>>>(
        x, WtE, WtM, WtS, enc_b, sig_b, msg_b, h_g, sig_bf, msg_g,
        src, dst, gcur, part);
    k_pb_aggr<<<NRANGE, 256, 0, stream>>>(
        gcur, part, sig_bf, (const char*)msg_g, (char*)comm);
    k_decode_m<<<(N_NODES + 63) / 64, 256, 0, stream>>>(
        h_g, comm, WtA0, WtA1, WtD, agg_b, dec_b, out);
}

// Round 16
// 95.595 us; speedup vs baseline: 1.5093x; 1.0020x over previous
//
#include <hip/hip_runtime.h>
#include <math.h>

#define N_NODES 50000
#define N_EDGES 800000
#define CAP 64     // bucket capacity per node (max degree <= 64, validated r7-r15)
#define NRANGE 782 // ceil(N_NODES/64) ranges of 64 nodes
#define PCAP 1280  // part capacity per range (mean 1023, +8 sigma)
#define EPBA 2560  // edges per partA block
#define NBA 313    // ceil(N_EDGES/EPBA)
#define NBE 391    // encode blocks: ceil(50000/128)

typedef __attribute__((ext_vector_type(8)))  short s16x8;   // 8 bf16 (4 VGPR)
typedef __attribute__((ext_vector_type(16))) float f32x16;  // MFMA acc
typedef unsigned int u32;
typedef unsigned short u16;

union U16B { uint4 u; s16x8 s; };

// f32 -> bf16 bits, round-to-nearest-even
__device__ __forceinline__ u32 bfr(float f) {
    u32 u = __float_as_uint(f);
    return (u + 0x7FFFu + ((u >> 16) & 1u)) >> 16;
}
__device__ __forceinline__ u32 pkbf(float a, float b) { return bfr(a) | (bfr(b) << 16); }
__device__ __forceinline__ float bf2f(u32 b) { return __uint_as_float(b << 16); }
// dot of a bf16x2 pair against another
__device__ __forceinline__ float dotpair(u32 a, u32 b) {
    return bf2f(a & 0xFFFFu) * bf2f(b & 0xFFFFu) + bf2f(a >> 16) * bf2f(b >> 16);
}

// Build an MFMA input frag (lane-dim = D-col, k = 8*(lane>>5)+e) from 8 f32
// D-regs of a 32x32x16 accumulator (rows (r&3)+8*(r>>2)+4*hh), via bf16 pack
// + half-wave exchange. d8 must be compile-time indexed by caller.
__device__ __forceinline__ uint4 buildfrag(const float* d8, int hh) {
    u32 P = pkbf(d8[0], d8[1]), Q = pkbf(d8[2], d8[3]);
    u32 R = pkbf(d8[4], d8[5]), S = pkbf(d8[6], d8[7]);
    u32 sP = (u32)__shfl_xor((int)P, 32);
    u32 sQ = (u32)__shfl_xor((int)Q, 32);
    u32 sR = (u32)__shfl_xor((int)R, 32);
    u32 sS = (u32)__shfl_xor((int)S, 32);
    uint4 f;
    f.x = hh ? sR : P;  f.y = hh ? sS : Q;
    f.z = hh ? R : sP;  f.w = hh ? S : sQ;
    return f;
}
#define BUILDF(OUT, ACC, Q, HH) do { \
    float _td[8]; \
    _Pragma("unroll") for (int _z = 0; _z < 8; ++_z) _td[_z] = (ACC)[(Q)*8 + _z]; \
    (OUT) = buildfrag(_td, HH); } while (0)
#define BUILDR(OUT, ACC, Q, HH) do { \
    float _td[8]; \
    _Pragma("unroll") for (int _z = 0; _z < 8; ++_z) _td[_z] = fmaxf((ACC)[(Q)*8 + _z], 0.f); \
    (OUT) = buildfrag(_td, HH); } while (0)

// ---------------------------------------------------------------------------
// prep: weights -> bf16, transposed [col][k] rows (256B), granule-XOR swizzled
// Also zeroes gcur (saves the memset dispatch).
// ---------------------------------------------------------------------------
__global__ __launch_bounds__(256) void k_prep(
    const float* __restrict__ enc_w, const float* __restrict__ msg_w,
    const float* __restrict__ sig_w, const float* __restrict__ agg_w,
    const float* __restrict__ dec_w,
    uint4* __restrict__ WtE, uint4* __restrict__ WtM, uint4* __restrict__ WtD,
    uint4* __restrict__ WtA0, uint4* __restrict__ WtA1, uint4* __restrict__ WtS,
    int* __restrict__ gcur)
{
    int gid = blockIdx.x * 256 + threadIdx.x;
    if (gid < NRANGE) gcur[gid] = 0;
    if (gid < 10240) {
        int m = gid >> 11, r = gid & 2047;
        int col = r >> 4, s = r & 15;
        const float* W; uint4* D; int kb = 0;
        if      (m == 0) { W = enc_w; D = WtE; }
        else if (m == 1) { W = msg_w; D = WtM; }
        else if (m == 2) { W = dec_w; D = WtD; }
        else if (m == 3) { W = agg_w; D = WtA0; }
        else             { W = agg_w; D = WtA1; kb = 128; }
        float v[8];
        #pragma unroll
        for (int j = 0; j < 8; ++j) v[j] = W[(size_t)(kb + s * 8 + j) * 128 + col];
        uint4 w;
        w.x = pkbf(v[0], v[1]); w.y = pkbf(v[2], v[3]);
        w.z = pkbf(v[4], v[5]); w.w = pkbf(v[6], v[7]);
        D[col * 16 + (s ^ (col & 7))] = w;
    } else if (gid < 10752) {
        int r = gid - 10240;
        int row = r >> 4, s = r & 15;
        float v[8];
        #pragma unroll
        for (int j = 0; j < 8; ++j)
            v[j] = (row < 16) ? sig_w[(size_t)(s * 8 + j) * 16 + row] : 0.0f;
        uint4 w;
        w.x = pkbf(v[0], v[1]); w.y = pkbf(v[2], v[3]);
        w.z = pkbf(v[4], v[5]); w.w = pkbf(v[6], v[7]);
        WtS[row * 16 + (s ^ (row & 7))] = w;
    }
}

// ---------------------------------------------------------------------------
// fused encode + partA. Weights direct from global (L2-resident). ALL global
// writes (h, msg) go through an LDS bounce so every store is a coalesced
// 256B row burst (was: per-lane scattered 16B pieces -> partial-line RMWs).
//   blockIdx <  NBE : MFMA encode (h, msg, sig)
//   blockIdx >= NBE : LDS radix partition of edges by range r = src>>6
// ---------------------------------------------------------------------------
__global__ __launch_bounds__(256) void k_enc_part(
    const float* __restrict__ x,
    const uint4* __restrict__ WtE, const uint4* __restrict__ WtM,
    const uint4* __restrict__ WtS,
    const float* __restrict__ enc_b, const float* __restrict__ sig_b,
    const float* __restrict__ msg_b,
    uint4* __restrict__ h_g, u32* __restrict__ sig_bf, uint4* __restrict__ msg_g,
    const int* __restrict__ src, const int* __restrict__ dst,
    int* __restrict__ gcur, u32* __restrict__ part)
{
    __shared__ uint4 LB[2048];   // x tile / h frags / msg frags / partA hist+base
    __shared__ float LS[2176];   // sig funnel

    const int t = threadIdx.x;

    if (blockIdx.x >= NBE) {
        // ---------------- partA path ----------------
        int* hist = (int*)LB;
        int* base = hist + NRANGE;
        const int e0 = (blockIdx.x - NBE) * EPBA;
        for (int i = t; i < NRANGE; i += 256) hist[i] = 0;
        __syncthreads();
        #pragma unroll 4
        for (int k = 0; k < EPBA / 256; ++k) {
            int e = e0 + k * 256 + t;
            if (e < N_EDGES) atomicAdd(&hist[src[e] >> 6], 1);
        }
        __syncthreads();
        for (int i = t; i < NRANGE; i += 256) {
            int h = hist[i];
            base[i] = h ? atomicAdd(&gcur[i], h) : 0;
        }
        __syncthreads();
        for (int i = t; i < NRANGE; i += 256) hist[i] = 0;
        __syncthreads();
        #pragma unroll 4
        for (int k = 0; k < EPBA / 256; ++k) {
            int e = e0 + k * 256 + t;
            if (e < N_EDGES) {
                int s = src[e], d = dst[e];
                int r = s >> 6;
                int p = base[r] + atomicAdd(&hist[r], 1);
                part[(size_t)r * PCAP + p] = ((u32)s << 16) | (u32)d;
            }
        }
        return;
    }

    // ---------------- encode path ----------------
    const int node0 = blockIdx.x * 128;
    int nrem = N_NODES - node0; if (nrem > 128) nrem = 128;
    const int lane = t & 63, wid = t >> 6;
    const int l31 = lane & 31, hh = lane >> 5;
    const int nloc = wid * 32 + l31;
    const int sw7 = l31 & 7;

    // stage x (f32->bf16, swizzled)
    #pragma unroll
    for (int it = 0; it < 8; ++it) {
        int idx = it * 256 + t;
        int nd = idx >> 4, s = idx & 15;
        float4 v0 = make_float4(0, 0, 0, 0), v1 = v0;
        if (nd < nrem) {
            const float4* px = (const float4*)(x + (size_t)(node0 + nd) * 128 + s * 8);
            v0 = px[0]; v1 = px[1];
        }
        uint4 w;
        w.x = pkbf(v0.x, v0.y); w.y = pkbf(v0.z, v0.w);
        w.z = pkbf(v1.x, v1.y); w.w = pkbf(v1.z, v1.w);
        LB[nd * 16 + (s ^ (nd & 7))] = w;
    }
    __syncthreads();

    const char* lb = (const char*)LB;
    const char* gwE = (const char*)WtE;
    const char* gwM = (const char*)WtM;
    const char* gwS = (const char*)WtS;

    // GEMM1: h^T = encW^T x^T  (weights direct from global, L2-resident)
    f32x16 a0 = {}, a1 = {}, a2 = {}, a3 = {};
    #pragma unroll
    for (int r = 0; r < 16; ++r) {
        int rr = (r & 3) + 8 * (r >> 2) + 4 * hh;
        a0[r] = enc_b[rr];      a1[r] = enc_b[32 + rr];
        a2[r] = enc_b[64 + rr]; a3[r] = enc_b[96 + rr];
    }
    #pragma unroll
    for (int ks = 0; ks < 8; ++ks) {
        int so = ((ks * 2 + hh) ^ sw7) << 4;
        s16x8 bf = *(const s16x8*)(lb + nloc * 256 + so);
        s16x8 w0 = *(const s16x8*)(gwE + l31 * 256 + so);
        s16x8 w1 = *(const s16x8*)(gwE + 8192 + l31 * 256 + so);
        s16x8 w2 = *(const s16x8*)(gwE + 16384 + l31 * 256 + so);
        s16x8 w3 = *(const s16x8*)(gwE + 24576 + l31 * 256 + so);
        a0 = __builtin_amdgcn_mfma_f32_32x32x16_bf16(w0, bf, a0, 0, 0, 0);
        a1 = __builtin_amdgcn_mfma_f32_32x32x16_bf16(w1, bf, a1, 0, 0, 0);
        a2 = __builtin_amdgcn_mfma_f32_32x32x16_bf16(w2, bf, a2, 0, 0, 0);
        a3 = __builtin_amdgcn_mfma_f32_32x32x16_bf16(w3, bf, a3, 0, 0, 0);
    }

    // h^T -> in-register bf16 fragments (k = h-col)
    uint4 hf[8];
    BUILDF(hf[0], a0, 0, hh); BUILDF(hf[1], a0, 1, hh);
    BUILDF(hf[2], a1, 0, hh); BUILDF(hf[3], a1, 1, hh);
    BUILDF(hf[4], a2, 0, hh); BUILDF(hf[5], a2, 1, hh);
    BUILDF(hf[6], a3, 0, hh); BUILDF(hf[7], a3, 1, hh);

    __syncthreads();   // all waves done reading x tile from LB
    // park h fragments in LB (swizzled rows)
    #pragma unroll
    for (int f = 0; f < 8; ++f) {
        int g = 2 * f + hh;
        LB[nloc * 16 + (g ^ sw7)] = hf[f];
    }

    // GEMM2: msg^T = msgW^T h^T  (B-operand = in-reg h frags) — overlaps h park
    f32x16 m0 = {}, m1 = {}, m2 = {}, m3 = {};
    #pragma unroll
    for (int r = 0; r < 16; ++r) {
        int rr = (r & 3) + 8 * (r >> 2) + 4 * hh;
        m0[r] = msg_b[rr];      m1[r] = msg_b[32 + rr];
        m2[r] = msg_b[64 + rr]; m3[r] = msg_b[96 + rr];
    }
    #pragma unroll
    for (int ks = 0; ks < 8; ++ks) {
        int so = ((ks * 2 + hh) ^ sw7) << 4;
        U16B hb; hb.u = hf[ks];
        s16x8 w0 = *(const s16x8*)(gwM + l31 * 256 + so);
        s16x8 w1 = *(const s16x8*)(gwM + 8192 + l31 * 256 + so);
        s16x8 w2 = *(const s16x8*)(gwM + 16384 + l31 * 256 + so);
        s16x8 w3 = *(const s16x8*)(gwM + 24576 + l31 * 256 + so);
        m0 = __builtin_amdgcn_mfma_f32_32x32x16_bf16(w0, hb.s, m0, 0, 0, 0);
        m1 = __builtin_amdgcn_mfma_f32_32x32x16_bf16(w1, hb.s, m1, 0, 0, 0);
        m2 = __builtin_amdgcn_mfma_f32_32x32x16_bf16(w2, hb.s, m2, 0, 0, 0);
        m3 = __builtin_amdgcn_mfma_f32_32x32x16_bf16(w3, hb.s, m3, 0, 0, 0);
    }
    uint4 mf[8];
    BUILDR(mf[0], m0, 0, hh); BUILDR(mf[1], m0, 1, hh);
    BUILDR(mf[2], m1, 0, hh); BUILDR(mf[3], m1, 1, hh);
    BUILDR(mf[4], m2, 0, hh); BUILDR(mf[5], m2, 1, hh);
    BUILDR(mf[6], m3, 0, hh); BUILDR(mf[7], m3, 1, hh);

    __syncthreads();   // h fragments parked
    // coalesced h_g write: 256B row bursts
    #pragma unroll
    for (int it = 0; it < 8; ++it) {
        int idx = it * 256 + t;
        if ((idx >> 4) < nrem) h_g[(size_t)node0 * 16 + idx] = LB[idx];
    }
    __syncthreads();   // h readout done; LB reusable
    // park msg fragments (LINEAR granule layout)
    #pragma unroll
    for (int f = 0; f < 8; ++f)
        LB[nloc * 16 + 2 * f + hh] = mf[f];

    // GEMM3: sig^T = sigW^T h^T — overlaps msg park
    f32x16 sg = {};
    #pragma unroll
    for (int r = 0; r < 8; ++r) {
        int rr = (r & 3) + 8 * (r >> 2) + 4 * hh;   // < 16
        sg[r] = sig_b[rr];
    }
    #pragma unroll
    for (int ks = 0; ks < 8; ++ks) {
        int so = ((ks * 2 + hh) ^ sw7) << 4;
        s16x8 aw = *(const s16x8*)(gwS + l31 * 256 + so);
        U16B hb; hb.u = hf[ks];
        sg = __builtin_amdgcn_mfma_f32_32x32x16_bf16(aw, hb.s, sg, 0, 0, 0);
    }
    float ss = 0.f;
    #pragma unroll
    for (int r = 0; r < 8; ++r) ss += sg[r] * sg[r];
    ss += __shfl_xor(ss, 32);
    float inv = 1.0f / fmaxf(sqrtf(ss), 1e-12f);
    #pragma unroll
    for (int r = 0; r < 8; ++r) {
        int sc = (r & 3) + 8 * (r >> 2) + 4 * hh;
        LS[nloc * 17 + sc] = sg[r] * inv;
    }
    __syncthreads();   // msg park + sig funnel complete

    // coalesced msg_g write
    #pragma unroll
    for (int it = 0; it < 8; ++it) {
        int idx = it * 256 + t;
        if ((idx >> 4) < nrem) msg_g[(size_t)node0 * 16 + idx] = LB[idx];
    }
    // sig rows -> global as bf16 pairs (8 u32 per node)
    #pragma unroll
    for (int it = 0; it < 4; ++it) {
        int idx = it * 256 + t;           // 1024 = 128 nodes x 8 u32
        int nd = idx >> 3, c2 = idx & 7;
        if (nd < nrem)
            sig_bf[(size_t)(node0 + nd) * 8 + c2] =
                pkbf(LS[nd * 17 + 2 * c2], LS[nd * 17 + 2 * c2 + 1]);
    }
}

// ---------------------------------------------------------------------------
// decode (MFMA): out = relu([h|comm]@agg_w+b) @ dec_w + b
// Block = 64 nodes, 4 waves: wave = (node half) x (64 col half).
// ---------------------------------------------------------------------------
__global__ __launch_bounds__(256) void k_decode_m(
    const uint4* __restrict__ h_g, const uint4* __restrict__ comm,
    const uint4* __restrict__ WtA0, const uint4* __restrict__ WtA1,
    const uint4* __restrict__ WtD,
    const float* __restrict__ agg_b, const float* __restrict__ dec_b,
    float* __restrict__ out)
{
    __shared__ uint4 LB[2048];   // Bcat [64][32 granules]; later Lcomb [64][16]
    __shared__ uint4 LW[2048];

    const int t = threadIdx.x;
    const int node0 = blockIdx.x * 64;
    int nrem = N_NODES - node0; if (nrem > 64) nrem = 64;
    const int lane = t & 63, wid = t >> 6;
    const int l31 = lane & 31, hh = lane >> 5;
    const int ng = wid & 1, cp = wid >> 1;
    const int nloc = ng * 32 + l31;
    const int sw7 = l31 & 7;

    // stage Bcat = [h | comm] bf16 (both pre-swizzled: linear copy)
    #pragma unroll
    for (int it = 0; it < 8; ++it) {
        int idx = it * 256 + t;
        int nd = idx >> 5, g = idx & 31;
        uint4 v = make_uint4(0, 0, 0, 0);
        if (nd < nrem)
            v = (g < 16) ? h_g[(size_t)(node0 + nd) * 16 + g]
                         : comm[(size_t)(node0 + nd) * 16 + (g - 16)];
        LB[nd * 32 + g] = v;
        LW[idx] = WtA0[idx];
    }
    __syncthreads();

    const char* lb = (const char*)LB;
    const char* lw = (const char*)LW;

    // GEMM-A: combined^T = aggW^T [h|comm]^T  (K = 256, staged in halves)
    f32x16 c0 = {}, c1 = {};
    #pragma unroll
    for (int r = 0; r < 16; ++r) {
        int rr = (r & 3) + 8 * (r >> 2) + 4 * hh;
        c0[r] = agg_b[cp * 64 + rr];
        c1[r] = agg_b[cp * 64 + 32 + rr];
    }
    #pragma unroll
    for (int ks = 0; ks < 8; ++ks) {
        int so = ((ks * 2 + hh) ^ sw7) << 4;
        s16x8 bf = *(const s16x8*)(lb + nloc * 512 + so);
        s16x8 w0 = *(const s16x8*)(lw + (cp * 64 + l31) * 256 + so);
        s16x8 w1 = *(const s16x8*)(lw + (cp * 64 + 32 + l31) * 256 + so);
        c0 = __builtin_amdgcn_mfma_f32_32x32x16_bf16(w0, bf, c0, 0, 0, 0);
        c1 = __builtin_amdgcn_mfma_f32_32x32x16_bf16(w1, bf, c1, 0, 0, 0);
    }
    __syncthreads();
    #pragma unroll
    for (int it = 0; it < 8; ++it) LW[it * 256 + t] = WtA1[it * 256 + t];
    __syncthreads();
    #pragma unroll
    for (int ks = 8; ks < 16; ++ks) {
        int so = ((ks * 2 + hh) ^ sw7) << 4;            // bit4 kept: comm half
        int so2 = (((ks - 8) * 2 + hh) ^ sw7) << 4;
        s16x8 bf = *(const s16x8*)(lb + nloc * 512 + so);
        s16x8 w0 = *(const s16x8*)(lw + (cp * 64 + l31) * 256 + so2);
        s16x8 w1 = *(const s16x8*)(lw + (cp * 64 + 32 + l31) * 256 + so2);
        c0 = __builtin_amdgcn_mfma_f32_32x32x16_bf16(w0, bf, c0, 0, 0, 0);
        c1 = __builtin_amdgcn_mfma_f32_32x32x16_bf16(w1, bf, c1, 0, 0, 0);
    }
    __syncthreads();   // all Bcat / WtA1 reads done

    // relu + build combined fragments; exchange across waves via LB (Lcomb)
    {
        uint4 cf[4];
        BUILDR(cf[0], c0, 0, hh); BUILDR(cf[1], c0, 1, hh);
        BUILDR(cf[2], c1, 0, hh); BUILDR(cf[3], c1, 1, hh);
        #pragma unroll
        for (int f = 0; f < 4; ++f) {
            int g = (cp * 4 + f) * 2 + hh;
            LB[nloc * 16 + (g ^ sw7)] = cf[f];
        }
    }
    #pragma unroll
    for (int it = 0; it < 8; ++it) LW[it * 256 + t] = WtD[it * 256 + t];
    __syncthreads();

    // GEMM-B: out = combined @ dec_w  (A = in-LDS combined frags, lane = outcol)
    f32x16 o0 = {}, o1 = {};
    {
        float b0 = dec_b[cp * 64 + l31], b1 = dec_b[cp * 64 + 32 + l31];
        #pragma unroll
        for (int r = 0; r < 16; ++r) { o0[r] = b0; o1[r] = b1; }
    }
    #pragma unroll
    for (int ks = 0; ks < 8; ++ks) {
        int so = ((ks * 2 + hh) ^ sw7) << 4;
        s16x8 af = *(const s16x8*)(lb + nloc * 256 + so);
        s16x8 w0 = *(const s16x8*)(lw + (cp * 64 + l31) * 256 + so);
        s16x8 w1 = *(const s16x8*)(lw + (cp * 64 + 32 + l31) * 256 + so);
        o0 = __builtin_amdgcn_mfma_f32_32x32x16_bf16(af, w0, o0, 0, 0, 0);
        o1 = __builtin_amdgcn_mfma_f32_32x32x16_bf16(af, w1, o1, 0, 0, 0);
    }
    #pragma unroll
    for (int r = 0; r < 16; ++r) {
        int nd = ng * 32 + (r & 3) + 8 * (r >> 2) + 4 * hh;
        if (nd < nrem) {
            float* row = out + (size_t)(node0 + nd) * 128 + cp * 64;
            row[l31]      = o0[r];
            row[32 + l31] = o1[r];
        }
    }
}

// ---------------------------------------------------------------------------
// fused partB + aggr: one block per 64-node range.
//  phase 1: bin entries into LDS (d, e=exp(sig.sig)) pairs; den via LDS atomics
//  phase 2: PV — 2 nodes/wave (half-wave, lane = 4 dims), 4-way unrolled with
//           batched independent gathers (4 outstanding L2 loads per half-wave).
// ---------------------------------------------------------------------------
__global__ __launch_bounds__(256) void k_pb_aggr(
    const int* __restrict__ gcur, const u32* __restrict__ part,
    const u32* __restrict__ sig_bf,
    const char* __restrict__ msg_g, char* __restrict__ comm)
{
    __shared__ int   cnt[64];
    __shared__ float lden[64];
    __shared__ int2  lde[64 * CAP];   // 32 KB (d, e) pairs

    const int t = threadIdx.x;
    const int r = blockIdx.x;
    const int node0 = r * 64;

    if (t < 64) { cnt[t] = 0; lden[t] = 0.f; }
    __syncthreads();

    const int total = gcur[r];
    for (int i = t; i < total; i += 256) {
        u32 en = part[(size_t)r * PCAP + i];
        int s = (int)(en >> 16), d = (int)(en & 0xFFFFu);
        const uint4* ps = (const uint4*)(sig_bf + (size_t)s * 8);
        const uint4* pd = (const uint4*)(sig_bf + (size_t)d * 8);
        uint4 sa = ps[0], sb = ps[1];
        uint4 da = pd[0], db = pd[1];
        float dot = dotpair(sa.x, da.x) + dotpair(sa.y, da.y)
                  + dotpair(sa.z, da.z) + dotpair(sa.w, da.w)
                  + dotpair(sb.x, db.x) + dotpair(sb.y, db.y)
                  + dotpair(sb.z, db.z) + dotpair(sb.w, db.w);
        float e = __expf(dot);   // |dot|<=1 (unit sigs): segment_max elision exact
        int sl = s & 63;
        int p = atomicAdd(&cnt[sl], 1);
        lde[sl * CAP + p] = make_int2(d, __float_as_int(e));
        atomicAdd(&lden[sl], e);
    }
    __syncthreads();

    // PV: wave wid covers nodes [wid*16, wid*16+16), 2 at a time (half-waves)
    const int lane = t & 63, wid = t >> 6;
    const int l31 = lane & 31, hh = lane >> 5;
    #pragma unroll
    for (int g = 0; g < 8; ++g) {
        const int nloc = wid * 16 + 2 * g + hh;
        const int node = node0 + nloc;
        const int cn = cnt[nloc];
        const int2* ld = &lde[nloc * CAP];
        float a0 = 0.f, a1 = 0.f, a2 = 0.f, a3 = 0.f;
        int k = 0;
        for (; k + 4 <= cn; k += 4) {
            int2 d0 = ld[k], d1 = ld[k + 1], d2 = ld[k + 2], d3 = ld[k + 3];
            uint2 m0 = *(const uint2*)(msg_g + (size_t)d0.x * 256 + 8 * l31);
            uint2 m1 = *(const uint2*)(msg_g + (size_t)d1.x * 256 + 8 * l31);
            uint2 m2 = *(const uint2*)(msg_g + (size_t)d2.x * 256 + 8 * l31);
            uint2 m3 = *(const uint2*)(msg_g + (size_t)d3.x * 256 + 8 * l31);
            float e0 = __int_as_float(d0.y), e1 = __int_as_float(d1.y);
            float e2 = __int_as_float(d2.y), e3 = __int_as_float(d3.y);
            a0 += e0 * bf2f(m0.x & 0xFFFFu); a1 += e0 * bf2f(m0.x >> 16);
            a2 += e0 * bf2f(m0.y & 0xFFFFu); a3 += e0 * bf2f(m0.y >> 16);
            a0 += e1 * bf2f(m1.x & 0xFFFFu); a1 += e1 * bf2f(m1.x >> 16);
            a2 += e1 * bf2f(m1.y & 0xFFFFu); a3 += e1 * bf2f(m1.y >> 16);
            a0 += e2 * bf2f(m2.x & 0xFFFFu); a1 += e2 * bf2f(m2.x >> 16);
            a2 += e2 * bf2f(m2.y & 0xFFFFu); a3 += e2 * bf2f(m2.y >> 16);
            a0 += e3 * bf2f(m3.x & 0xFFFFu); a1 += e3 * bf2f(m3.x >> 16);
            a2 += e3 * bf2f(m3.y & 0xFFFFu); a3 += e3 * bf2f(m3.y >> 16);
        }
        for (; k < cn; ++k) {
            int2 de = ld[k];
            float e = __int_as_float(de.y);
            uint2 m = *(const uint2*)(msg_g + (size_t)de.x * 256 + 8 * l31);
            a0 += e * bf2f(m.x & 0xFFFFu);
            a1 += e * bf2f(m.x >> 16);
            a2 += e * bf2f(m.y & 0xFFFFu);
            a3 += e * bf2f(m.y >> 16);
        }
        float den = lden[nloc];
        float inv = (den > 0.f) ? (1.0f / den) : 0.f;
        if (node < N_NODES) {
            uint2 w;
            w.x = pkbf(a0 * inv, a1 * inv);
            w.y = pkbf(a2 * inv, a3 * inv);
            *(uint2*)(comm + (size_t)node * 256 + ((8 * l31) ^ ((node & 7) << 4))) = w;
        }
    }
}

// ---------------------------------------------------------------------------
extern "C" void kernel_launch(void* const* d_in, const int* in_sizes, int n_in,
                              void* d_out, int out_size, void* d_ws, size_t ws_size,
                              hipStream_t stream)
{
    const float* x     = (const float*)d_in[0];
    const int*   ei    = (const int*)  d_in[1];
    const float* enc_w = (const float*)d_in[2];
    const float* enc_b = (const float*)d_in[3];
    const float* sig_w = (const float*)d_in[4];
    const float* sig_b = (const float*)d_in[5];
    const float* msg_w = (const float*)d_in[6];
    const float* msg_b = (const float*)d_in[7];
    const float* agg_w = (const float*)d_in[8];
    const float* agg_b = (const float*)d_in[9];
    const float* dec_w = (const float*)d_in[10];
    const float* dec_b = (const float*)d_in[11];
    float* out = (float*)d_out;

    const int* src = ei;            // edge_index[0]
    const int* dst = ei + N_EDGES;  // edge_index[1]

    // workspace layout (bytes), ~45 MB
    char* p = (char*)d_ws;
    uint4* h_g   = (uint4*)p;  p += (size_t)N_NODES * 256;  // bf16 rows, swizzled
    uint4* msg_g = (uint4*)p;  p += (size_t)N_NODES * 256;  // bf16 rows, LINEAR
    uint4* comm  = (uint4*)p;  p += (size_t)N_NODES * 256;  // bf16 rows, swizzled
    u32*   sig_bf = (u32*)p;   p += (size_t)N_NODES * 32;   // bf16 sig rows
    u32*   part   = (u32*)p;   p += (size_t)NRANGE * PCAP * 4;
    int*   gcur   = (int*)p;   p += 4096;
    uint4* WtE  = (uint4*)p; p += 32768;
    uint4* WtM  = (uint4*)p; p += 32768;
    uint4* WtD  = (uint4*)p; p += 32768;
    uint4* WtA0 = (uint4*)p; p += 32768;
    uint4* WtA1 = (uint4*)p; p += 32768;
    uint4* WtS  = (uint4*)p; p += 8192;

    k_prep<<<42, 256, 0, stream>>>(enc_w, msg_w, sig_w, agg_w, dec_w,
                                   WtE, WtM, WtD, WtA0, WtA1, WtS, gcur);
    k_enc_part<<<NBE + NBA, 256, 0, stream>>>(
        x, WtE, WtM, WtS, enc_b, sig_b, msg_b, h_g, sig_bf, msg_g,
        src, dst, gcur, part);
    k_pb_aggr<<<NRANGE, 256, 0, stream>>>(
        gcur, part, sig_bf, (const char*)msg_g, (char*)comm);
    k_decode_m<<<(N_NODES + 63) / 64, 256, 0, stream>>>(
        h_g, comm, WtA0, WtA1, WtD, agg_b, dec_b, out);
}